// Round 3
// baseline (658.244 us; speedup 1.0000x reference)
//
#include <hip/hip_runtime.h>
#include <math.h>

#define D 256
#define DCAT 768
#define NPX 128

typedef __attribute__((ext_vector_type(8))) short bf16x8;
typedef __attribute__((ext_vector_type(4))) float f32x4;

__device__ __forceinline__ short cvt_bf16(float f){
  union { float f; unsigned u; } v; v.f = f;
  unsigned r = v.u + 0x7FFF + ((v.u >> 16) & 1);   // RNE
  return (short)(r >> 16);
}
__device__ __forceinline__ float bf2f(short s){
  union { float f; unsigned u; } v; v.u = ((unsigned)(unsigned short)s) << 16;
  return v.f;
}

__device__ __forceinline__ float waveSum(float v){
#pragma unroll
  for(int o=32;o>=1;o>>=1) v += __shfl_xor(v,o,64);
  return v;
}
__device__ __forceinline__ float waveMax(float v){
#pragma unroll
  for(int o=32;o>=1;o>>=1) v = fmaxf(v,__shfl_xor(v,o,64));
  return v;
}

__global__ void k_tanh(const float* __restrict__ p, float* __restrict__ tp, int n){
  int i = blockIdx.x*blockDim.x+threadIdx.x;
  if(i<n) tp[i]=tanhf(p[i]);
}

__global__ void k_rowstart(const int* __restrict__ adj_row, int* __restrict__ rs, int n, int e){
  int i = blockIdx.x*blockDim.x+threadIdx.x;
  if(i>n) return;
  int lo=0, hi=e;
  while(lo<hi){ int mid=(lo+hi)>>1; if(adj_row[mid]<i) lo=mid+1; else hi=mid; }
  rs[i]=lo;
}

__global__ void k_flag(const int* __restrict__ idx, unsigned char* __restrict__ flag, int k){
  int i = blockIdx.x*blockDim.x+threadIdx.x;
  if(i<k) flag[idx[i]] = 1;
}

__global__ void k_relprep(const float* __restrict__ rel_emb, const float* __restrict__ attn,
                          float* __restrict__ ss_rel, float* __restrict__ att_n, int R_){
  __shared__ float sm[4];
  int r = blockIdx.x; int d = threadIdx.x;
  float v = rel_emb[(size_t)r*D+d];
  int lane=threadIdx.x&63, wid=threadIdx.x>>6;
  float s = waveSum(v*v);
  if(lane==0) sm[wid]=s;
  __syncthreads();
  if(threadIdx.x==0) ss_rel[r]=sm[0]+sm[1]+sm[2]+sm[3];
  __syncthreads();
  for(int l=0;l<2;l++){
    float dd = waveSum(v*attn[l*D+d]);
    if(lane==0) sm[wid]=dd;
    __syncthreads();
    if(threadIdx.x==0) att_n[(size_t)l*R_+r]=sm[0]+sm[1]+sm[2]+sm[3];
    __syncthreads();
  }
}

__global__ void k_relW(const float* __restrict__ rel_emb, const float* __restrict__ W,
                       const float* __restrict__ ak, float* __restrict__ relW,
                       float* __restrict__ att_t, int R_){
  __shared__ float sm[4];
  int r=blockIdx.x, d=threadIdx.x;
  const float* row = rel_emb + (size_t)r*D;
  float acc=0.f;
#pragma unroll 4
  for(int k=0;k<D;k++) acc = fmaf(row[k], W[(size_t)k*D+d], acc);
  relW[(size_t)r*D+d]=acc;
  int lane=threadIdx.x&63, wid=threadIdx.x>>6;
  float dd = waveSum(acc*ak[d]);
  if(lane==0) sm[wid]=dd;
  __syncthreads();
  if(threadIdx.x==0) att_t[r]=sm[0]+sm[1]+sm[2]+sm[3];
}

__global__ void k_init0(const float* __restrict__ features, const float* __restrict__ tp,
                        float* __restrict__ outcat, short* __restrict__ outcatb, long total){
  long i = (long)blockIdx.x*blockDim.x+threadIdx.x;
  if(i >= total) return;
  int row = (int)(i>>8), d = (int)(i&255);
  float v = features[i]*tp[row];
  outcat[(size_t)row*DCAT + d] = v;
  outcatb[(size_t)row*DCAT + d] = cvt_bf16(v);
}

__global__ void k_agg(const int* __restrict__ rs, const int* __restrict__ adj_col,
                      const int* __restrict__ rel_ids, const float* __restrict__ rel_vals,
                      const unsigned char* __restrict__ flag, const float* __restrict__ tp,
                      const float* __restrict__ ss_rel, const float* __restrict__ att_n,
                      const float* __restrict__ att_t, const float* __restrict__ rel_emb,
                      const float* __restrict__ relW, float* __restrict__ outcat,
                      short* __restrict__ outcatb, int n, int layer){
  int wid = threadIdx.x>>6, lane = threadIdx.x&63;
  int node = blockIdx.x*4 + wid;
  if(node>=n) return;
  int s = rs[node], e = rs[node+1];
  float4 acc = make_float4(0.f,0.f,0.f,0.f);
  if(e > s){
    float mx = -INFINITY;
    for(int i=s+lane;i<e;i+=64){
      int rid = rel_ids[i]; float rv = rel_vals[i];
      float a = 0.f;
      if(rv>0.f){
        float t = tp[adj_col[i]];
        float sc = rv*rsqrtf(fmaxf(rv*rv*ss_rel[rid],1e-12f));
        a = t*sc*(flag[i]? att_t[rid] : att_n[rid]);
      }
      mx = fmaxf(mx,a);
    }
    mx = waveMax(mx);
    float se = 0.f;
    for(int i=s+lane;i<e;i+=64){
      int rid = rel_ids[i]; float rv = rel_vals[i];
      float a = 0.f;
      if(rv>0.f){
        float t = tp[adj_col[i]];
        float sc = rv*rsqrtf(fmaxf(rv*rv*ss_rel[rid],1e-12f));
        a = t*sc*(flag[i]? att_t[rid] : att_n[rid]);
      }
      se += expf(a-mx);
    }
    se = waveSum(se);
    float inv = 1.f/se;
    for(int i=s;i<e;i++){
      int rid = rel_ids[i]; float rv = rel_vals[i]; int col = adj_col[i];
      float4 nb = *(const float4*)(outcat + (size_t)col*DCAT + layer*D + lane*4);
      float w; float coef = 0.f; float4 rb = make_float4(0.f,0.f,0.f,0.f);
      if(rv>0.f){
        float t = tp[col];
        float sc = rv*rsqrtf(fmaxf(rv*rv*ss_rel[rid],1e-12f));
        const float* rp = (flag[i]? relW : rel_emb) + (size_t)rid*D;
        rb = *(const float4*)(rp + lane*4);
        float a = t*sc*(flag[i]? att_t[rid]:att_n[rid]);
        w = expf(a-mx)*inv;
        float dp = nb.x*rb.x+nb.y*rb.y+nb.z*rb.z+nb.w*rb.w;
        dp = waveSum(dp);
        coef = 2.f*t*t*sc*sc*dp;
      } else {
        w = expf(-mx)*inv;
      }
      acc.x += w*(nb.x - coef*rb.x);
      acc.y += w*(nb.y - coef*rb.y);
      acc.z += w*(nb.z - coef*rb.z);
      acc.w += w*(nb.w - coef*rb.w);
    }
  }
  float t = tp[node];
  float4 o = make_float4(acc.x*t, acc.y*t, acc.z*t, acc.w*t);
  *(float4*)(outcat + (size_t)node*DCAT + (layer+1)*D + lane*4) = o;
  short4 ob; ob.x=cvt_bf16(o.x); ob.y=cvt_bf16(o.y); ob.z=cvt_bf16(o.z); ob.w=cvt_bf16(o.w);
  *(short4*)(outcatb + (size_t)node*DCAT + (layer+1)*D + lane*4) = ob;
}

// l2-normalize proxy rows -> bf16 [128][768]
__global__ void k_proxynorm(const float* __restrict__ proxy, short* __restrict__ pn){
  __shared__ float sm[4];
  int j = blockIdx.x;
  float ssum=0.f;
  for(int d=threadIdx.x; d<DCAT; d+=256){ float v=proxy[(size_t)j*DCAT+d]; ssum+=v*v; }
  int lane=threadIdx.x&63, wid=threadIdx.x>>6;
  ssum = waveSum(ssum);
  if(lane==0) sm[wid]=ssum;
  __syncthreads();
  float scale = rsqrtf(fmaxf(sm[0]+sm[1]+sm[2]+sm[3],1e-12f));
  for(int d=threadIdx.x; d<DCAT; d+=256)
    pn[(size_t)j*DCAT + d] = cvt_bf16(proxy[(size_t)j*DCAT+d]*scale);
}

// plain cast fp32 -> bf16
__global__ void k_cast(const float* __restrict__ in, short* __restrict__ out, long total){
  long i = (long)blockIdx.x*blockDim.x+threadIdx.x;
  if(i<total) out[i]=cvt_bf16(in[i]);
}

// transpose-cast with sign: in fp32 [R][C] -> out bf16 [C][R] (* sign)
__global__ void k_tcast(const float* __restrict__ in, short* __restrict__ out, int R, int C, float sign){
  __shared__ float tile[32][33];
  int bx = blockIdx.x*32, by = blockIdx.y*32;
  for(int i=threadIdx.y;i<32;i+=8){
    int rr = by+i, cc = bx+threadIdx.x;
    if(rr<R && cc<C) tile[i][threadIdx.x] = in[(size_t)rr*C + cc];
  }
  __syncthreads();
  for(int i=threadIdx.y;i<32;i+=8){
    int cc = bx+i, rr = by+threadIdx.x;
    if(cc<C && rr<R) out[(size_t)cc*R + rr] = cvt_bf16(sign*tile[threadIdx.x][i]);
  }
}

// per-row l2 normalize (reads bf16 mirror) -> bf16 A operand for GEMM-1
__global__ void k_sn2(const short* __restrict__ outcatb, short* __restrict__ An, int n){
  int wid=threadIdx.x>>6, lane=threadIdx.x&63;
  int row = blockIdx.x*4+wid; if(row>=n) return;
  const short* o = outcatb + (size_t)row*DCAT;
  short4 v[3]; float f[3][4];
  float ss=0.f;
#pragma unroll
  for(int c=0;c<3;c++){
    v[c] = *(const short4*)(o + c*256 + lane*4);
    f[c][0]=bf2f(v[c].x); f[c][1]=bf2f(v[c].y); f[c][2]=bf2f(v[c].z); f[c][3]=bf2f(v[c].w);
    ss += f[c][0]*f[c][0]+f[c][1]*f[c][1]+f[c][2]*f[c][2]+f[c][3]*f[c][3];
  }
  ss = waveSum(ss);
  float s = rsqrtf(fmaxf(ss,1e-12f));
  short* a = An + (size_t)row*DCAT;
#pragma unroll
  for(int c=0;c<3;c++){
    short4 t;
    t.x = cvt_bf16(f[c][0]*s); t.y = cvt_bf16(f[c][1]*s);
    t.z = cvt_bf16(f[c][2]*s); t.w = cvt_bf16(f[c][3]*s);
    *(short4*)(a + c*256 + lane*4) = t;
  }
}

// row softmax over 128 logits -> bf16 probs
__global__ void k_sm128(const float* __restrict__ P, short* __restrict__ Pb, int n){
  int wid=threadIdx.x>>6, lane=threadIdx.x&63;
  int row=blockIdx.x*4+wid; if(row>=n) return;
  const float* pr = P + (size_t)row*NPX;
  float a=pr[lane], b=pr[lane+64];
  float m = waveMax(fmaxf(a,b));
  float ea=__expf(a-m), eb=__expf(b-m);
  float s = waveSum(ea+eb);
  short* pb = Pb + (size_t)row*NPX;
  pb[lane]=cvt_bf16(ea/s); pb[lane+64]=cvt_bf16(eb/s);
}

// ---------------- MFMA GEMM (m97 structure): C[M,NTOT] = A[M,KC] @ Bt[NTOT,KC]^T ----
template<int NTOT, int KC, int V>
__global__ __launch_bounds__(256,2) void k_mfma(
    const short* __restrict__ A, const short* __restrict__ Bt,
    float* __restrict__ out1, int M)
{
  __shared__ short smem[2][2][128*32];
  const int tid = threadIdx.x;
  const int lane = tid & 63, w = tid >> 6;
  const int wm = w >> 1, wn = w & 1;
  const int bn = blockIdx.x * 128, bm = blockIdx.y * 128;

  const short* Ag = A  + (size_t)bm * KC;
  const short* Bg = Bt + (size_t)bn * KC;

  auto stage = [&](int buf, int k0){
#pragma unroll
    for(int c=0;c<2;++c){
      int u = c*256 + tid;
      int row = u >> 2, cb = (u & 3) * 8;
      const short* ga = Ag + (size_t)row * KC + k0 + cb;
      short* la = &smem[buf][0][u*8];
      __builtin_amdgcn_global_load_lds((const __attribute__((address_space(1))) unsigned int*)ga,
                                       (__attribute__((address_space(3))) unsigned int*)la, 16, 0, 0);
      const short* gb = Bg + (size_t)row * KC + k0 + cb;
      short* lb = &smem[buf][1][u*8];
      __builtin_amdgcn_global_load_lds((const __attribute__((address_space(1))) unsigned int*)gb,
                                       (__attribute__((address_space(3))) unsigned int*)lb, 16, 0, 0);
    }
  };

  f32x4 acc[4][4] = {};
  const int lr = lane & 15, kg = lane >> 4;

  stage(0, 0);
  __syncthreads();
  constexpr int NT = KC / 32;
  for(int t=0; t<NT; ++t){
    int cur = t & 1;
    if(t+1 < NT) stage(cur^1, (t+1)*32);
    const short* Al = &smem[cur][0][0];
    const short* Bl = &smem[cur][1][0];
    bf16x8 af[4], bfr[4];
#pragma unroll
    for(int i=0;i<4;++i)
      af[i] = *(const bf16x8*)(Al + (wm*64 + i*16 + lr)*32 + kg*8);
#pragma unroll
    for(int j=0;j<4;++j)
      bfr[j] = *(const bf16x8*)(Bl + (wn*64 + j*16 + lr)*32 + kg*8);
#pragma unroll
    for(int i=0;i<4;++i)
#pragma unroll
      for(int j=0;j<4;++j)
        acc[i][j] = __builtin_amdgcn_mfma_f32_16x16x32_bf16(af[i], bfr[j], acc[i][j], 0, 0, 0);
    __syncthreads();
  }

  const int row0 = bm + wm*64 + (lane>>4)*4;
  const int col0 = bn + wn*64 + lr;
#pragma unroll
  for(int i=0;i<4;++i){
#pragma unroll
    for(int j=0;j<4;++j){
      int col = col0 + j*16;
#pragma unroll
      for(int r=0;r<4;++r){
        int row = row0 + i*16 + r;
        if(row < M) out1[(size_t)row * NTOT + col] = acc[i][j][r];
      }
    }
  }
}

// ---------------- fused gate kernel -------------------------------------------------
// acc1 = Pb@MxTn^T (K=128, MxTn = -(proxy@gk)^T) + outcatb@gkT^T (K=768)  == pf@gk
// acc3 = Pb@Bt2^T  (K=128)                                               == P@proxy
// out  = outcat - (1-sigmoid(acc1))*acc3
__global__ __launch_bounds__(256,2) void k_gfused(
    const short* __restrict__ outcatb, const short* __restrict__ Pb,
    const short* __restrict__ gkT, const short* __restrict__ MxTn,
    const short* __restrict__ Bt2, float* __restrict__ outio, int M)
{
  __shared__ short smem[2][2][128*32];
  const int tid = threadIdx.x;
  const int lane = tid & 63, w = tid >> 6;
  const int wm = w >> 1, wn = w & 1;
  const int bn = blockIdx.x * 128, bm = blockIdx.y * 128;
  const int lr = lane & 15, kg = lane >> 4;

  f32x4 acc1[4][4] = {};
  f32x4 acc3[4][4] = {};

  auto gemm = [&](const short* Ag, const short* Bg, int KC, f32x4 (&acc)[4][4]){
    auto stage = [&](int buf, int k0){
#pragma unroll
      for(int c=0;c<2;++c){
        int u = c*256 + tid;
        int row = u >> 2, cb = (u & 3) * 8;
        const short* ga = Ag + (size_t)row * KC + k0 + cb;
        short* la = &smem[buf][0][u*8];
        __builtin_amdgcn_global_load_lds((const __attribute__((address_space(1))) unsigned int*)ga,
                                         (__attribute__((address_space(3))) unsigned int*)la, 16, 0, 0);
        const short* gb = Bg + (size_t)row * KC + k0 + cb;
        short* lb = &smem[buf][1][u*8];
        __builtin_amdgcn_global_load_lds((const __attribute__((address_space(1))) unsigned int*)gb,
                                         (__attribute__((address_space(3))) unsigned int*)lb, 16, 0, 0);
      }
    };
    stage(0, 0);
    __syncthreads();
    const int NT = KC / 32;
    for(int t=0; t<NT; ++t){
      int cur = t & 1;
      if(t+1 < NT) stage(cur^1, (t+1)*32);
      const short* Al = &smem[cur][0][0];
      const short* Bl = &smem[cur][1][0];
      bf16x8 af[4], bfr[4];
#pragma unroll
      for(int i=0;i<4;++i)
        af[i] = *(const bf16x8*)(Al + (wm*64 + i*16 + lr)*32 + kg*8);
#pragma unroll
      for(int j=0;j<4;++j)
        bfr[j] = *(const bf16x8*)(Bl + (wn*64 + j*16 + lr)*32 + kg*8);
#pragma unroll
      for(int i=0;i<4;++i)
#pragma unroll
        for(int j=0;j<4;++j)
          acc[i][j] = __builtin_amdgcn_mfma_f32_16x16x32_bf16(af[i], bfr[j], acc[i][j], 0, 0, 0);
      __syncthreads();
    }
  };

  gemm(Pb + (size_t)bm * NPX,       MxTn + (size_t)bn * NPX, NPX,  acc1);
  gemm(outcatb + (size_t)bm * DCAT, gkT  + (size_t)bn * DCAT, DCAT, acc1);
  gemm(Pb + (size_t)bm * NPX,       Bt2  + (size_t)bn * NPX, NPX,  acc3);

  const int row0 = bm + wm*64 + (lane>>4)*4;
  const int col0 = bn + wn*64 + lr;
#pragma unroll
  for(int i=0;i<4;++i){
#pragma unroll
    for(int j=0;j<4;++j){
      int col = col0 + j*16;
#pragma unroll
      for(int r=0;r<4;++r){
        int row = row0 + i*16 + r;
        if(row < M){
          size_t idx = (size_t)row * DCAT + col;
          float g = 1.f/(1.f+__expf(-acc1[i][j][r]));
          outio[idx] = outio[idx] - (1.f-g)*acc3[i][j][r];
        }
      }
    }
  }
}

__global__ void k_copyp(const float* __restrict__ p, float* __restrict__ out, int n){
  int i = blockIdx.x*blockDim.x+threadIdx.x;
  if(i<n) out[i]=p[i];
}

extern "C" void kernel_launch(void* const* d_in, const int* in_sizes, int n_in,
                              void* d_out, int out_size, void* d_ws, size_t ws_size,
                              hipStream_t stream){
  const float* features = (const float*)d_in[0];
  const float* rel_emb  = (const float*)d_in[1];
  const float* p        = (const float*)d_in[2];
  const float* w_keys   = (const float*)d_in[3];
  const float* attn     = (const float*)d_in[4];
  const float* proxy    = (const float*)d_in[5];
  const float* gatek    = (const float*)d_in[6];
  const float* rel_vals = (const float*)d_in[7];
  const int* adj_row    = (const int*)d_in[8];
  const int* adj_col    = (const int*)d_in[9];
  const int* rel_ids    = (const int*)d_in[10];
  const int* new_idx    = (const int*)d_in[11];

  const int n    = in_sizes[2];
  const int r    = in_sizes[1]/D;
  const int e    = in_sizes[7];
  const int ksel = in_sizes[11];
  const size_t Mpad = ((size_t)n + 127) & ~(size_t)127;

  char* ws = (char*)d_ws;
  size_t off=0;
  auto alloc=[&](size_t bytes)->void*{ void* pp = ws+off; off=(off+bytes+255)&~(size_t)255; return pp; };
  float* tp      = (float*)alloc((size_t)n*4);
  int*   rs      = (int*)alloc((size_t)(n+1)*4);
  unsigned char* flag = (unsigned char*)alloc((size_t)e);
  float* ss_rel  = (float*)alloc((size_t)r*4);
  float* att_n   = (float*)alloc((size_t)2*r*4);
  float* att_t   = (float*)alloc((size_t)2*r*4);
  float* relW    = (float*)alloc((size_t)2*r*D*4);
  short* pn      = (short*)alloc((size_t)NPX*DCAT*2);   // l2n(proxy) bf16
  short* proxyb  = (short*)alloc((size_t)NPX*DCAT*2);   // proxy bf16
  short* Bt2     = (short*)alloc((size_t)DCAT*NPX*2);   // proxy^T bf16
  short* gkT     = (short*)alloc((size_t)DCAT*DCAT*2);  // gate_kernel^T bf16
  short* MxTn    = (short*)alloc((size_t)DCAT*NPX*2);   // -(proxy@gk)^T bf16
  float* MxF     = (float*)alloc((size_t)NPX*DCAT*4);   // proxy@gk fp32
  short* outcatb = (short*)alloc(Mpad*DCAT*2);          // bf16 mirror of outcat
  short* An      = (short*)alloc(Mpad*DCAT*2);          // l2n(outcat) bf16
  short* Pb      = (short*)alloc(Mpad*NPX*2);           // softmax probs bf16
  float* P       = (float*)alloc(Mpad*NPX*4);           // proxy-att logits fp32

  float* outcat = (float*)d_out;
  float* pout   = (float*)d_out + (size_t)n*DCAT;

  hipMemsetAsync(flag, 0, (size_t)e, stream);
  k_tanh<<<(n+255)/256,256,0,stream>>>(p,tp,n);
  k_rowstart<<<(n+256)/256,256,0,stream>>>(adj_row,rs,n,e);
  k_flag<<<(ksel+255)/256,256,0,stream>>>(new_idx,flag,ksel);
  k_relprep<<<r,256,0,stream>>>(rel_emb,attn,ss_rel,att_n,r);
  for(int l=0;l<2;l++)
    k_relW<<<r,256,0,stream>>>(rel_emb, w_keys+(size_t)l*D*D, attn+(size_t)l*D,
                               relW+(size_t)l*r*D, att_t+(size_t)l*r, r);
  k_proxynorm<<<NPX,256,0,stream>>>(proxy,pn);
  {
    long tpx = (long)NPX*DCAT;
    k_cast<<<(int)((tpx+255)/256),256,0,stream>>>(proxy, proxyb, tpx);
    dim3 tb(32,8);
    k_tcast<<<dim3(DCAT/32, NPX/32), tb, 0, stream>>>(proxy, Bt2, NPX, DCAT, 1.f);
    k_tcast<<<dim3(DCAT/32, DCAT/32), tb, 0, stream>>>(gatek, gkT, DCAT, DCAT, 1.f);
    // Mx = proxy @ gk  [128,768]  then MxTn = -Mx^T bf16
    k_mfma<DCAT, DCAT, 0><<<dim3(DCAT/128, 1), 256, 0, stream>>>(proxyb, gkT, MxF, NPX);
    k_tcast<<<dim3(DCAT/32, NPX/32), tb, 0, stream>>>(MxF, MxTn, NPX, DCAT, -1.f);
  }
  long tot0 = (long)n*D;
  k_init0<<<(int)((tot0+255)/256),256,0,stream>>>(features,tp,outcat,outcatb,tot0);
  for(int l=0;l<2;l++)
    k_agg<<<(n+3)/4,256,0,stream>>>(rs,adj_col,rel_ids,rel_vals,flag,tp,ss_rel,
                                    att_n+(size_t)l*r, att_t+(size_t)l*r, rel_emb,
                                    relW+(size_t)l*r*D, outcat, outcatb, n, l);
  k_sn2<<<(n+3)/4,256,0,stream>>>(outcatb,An,n);

  int mt = (int)(Mpad/128);
  // GEMM-1: P = An @ pn^T   [M,128], K=768
  k_mfma<NPX, DCAT, 0><<<dim3(1, mt), 256, 0, stream>>>(An, pn, P, n);
  k_sm128<<<(n+3)/4,256,0,stream>>>(P,Pb,n);
  // fused gate + output
  k_gfused<<<dim3(DCAT/128, mt), 256, 0, stream>>>(outcatb, Pb, gkT, MxTn, Bt2, outcat, n);
  k_copyp<<<(n+255)/256,256,0,stream>>>(p,pout,n);
}

// Round 4
// 594.699 us; speedup vs baseline: 1.1069x; 1.1069x over previous
//
#include <hip/hip_runtime.h>
#include <math.h>

#define D 256
#define DCAT 768
#define NPX 128
#define QSTR 896   // Q row stride: [outcat(768) | P(128)] bf16

typedef __attribute__((ext_vector_type(8))) short bf16x8;
typedef __attribute__((ext_vector_type(4))) float f32x4;

__device__ __forceinline__ short cvt_bf16(float f){
  union { float f; unsigned u; } v; v.f = f;
  unsigned r = v.u + 0x7FFF + ((v.u >> 16) & 1);   // RNE
  return (short)(r >> 16);
}
__device__ __forceinline__ float bf2f(short s){
  union { float f; unsigned u; } v; v.u = ((unsigned)(unsigned short)s) << 16;
  return v.f;
}

__device__ __forceinline__ float waveSum(float v){
#pragma unroll
  for(int o=32;o>=1;o>>=1) v += __shfl_xor(v,o,64);
  return v;
}
__device__ __forceinline__ float waveMax(float v){
#pragma unroll
  for(int o=32;o>=1;o>>=1) v = fmaxf(v,__shfl_xor(v,o,64));
  return v;
}

__global__ void k_tanh(const float* __restrict__ p, float* __restrict__ tp, int n){
  int i = blockIdx.x*blockDim.x+threadIdx.x;
  if(i<n) tp[i]=tanhf(p[i]);
}

__global__ void k_rowstart(const int* __restrict__ adj_row, int* __restrict__ rs, int n, int e){
  int i = blockIdx.x*blockDim.x+threadIdx.x;
  if(i>n) return;
  int lo=0, hi=e;
  while(lo<hi){ int mid=(lo+hi)>>1; if(adj_row[mid]<i) lo=mid+1; else hi=mid; }
  rs[i]=lo;
}

__global__ void k_flag(const int* __restrict__ idx, unsigned char* __restrict__ flag, int k){
  int i = blockIdx.x*blockDim.x+threadIdx.x;
  if(i<k) flag[idx[i]] = 1;
}

__global__ void k_relprep(const float* __restrict__ rel_emb, const float* __restrict__ attn,
                          float* __restrict__ ss_rel, float* __restrict__ att_n, int R_){
  __shared__ float sm[4];
  int r = blockIdx.x; int d = threadIdx.x;
  float v = rel_emb[(size_t)r*D+d];
  int lane=threadIdx.x&63, wid=threadIdx.x>>6;
  float s = waveSum(v*v);
  if(lane==0) sm[wid]=s;
  __syncthreads();
  if(threadIdx.x==0) ss_rel[r]=sm[0]+sm[1]+sm[2]+sm[3];
  __syncthreads();
  for(int l=0;l<2;l++){
    float dd = waveSum(v*attn[l*D+d]);
    if(lane==0) sm[wid]=dd;
    __syncthreads();
    if(threadIdx.x==0) att_n[(size_t)l*R_+r]=sm[0]+sm[1]+sm[2]+sm[3];
    __syncthreads();
  }
}

__global__ void k_relW(const float* __restrict__ rel_emb, const float* __restrict__ W,
                       const float* __restrict__ ak, float* __restrict__ relW,
                       float* __restrict__ att_t, int R_){
  __shared__ float sm[4];
  int r=blockIdx.x, d=threadIdx.x;
  const float* row = rel_emb + (size_t)r*D;
  float acc=0.f;
#pragma unroll 4
  for(int k=0;k<D;k++) acc = fmaf(row[k], W[(size_t)k*D+d], acc);
  relW[(size_t)r*D+d]=acc;
  int lane=threadIdx.x&63, wid=threadIdx.x>>6;
  float dd = waveSum(acc*ak[d]);
  if(lane==0) sm[wid]=dd;
  __syncthreads();
  if(threadIdx.x==0) att_t[r]=sm[0]+sm[1]+sm[2]+sm[3];
}

__global__ void k_init0(const float* __restrict__ features, const float* __restrict__ tp,
                        short* __restrict__ Q, long total){
  long i = (long)blockIdx.x*blockDim.x+threadIdx.x;
  if(i >= total) return;
  int row = (int)(i>>8), d = (int)(i&255);
  Q[(size_t)row*QSTR + d] = cvt_bf16(features[i]*tp[row]);
}

// one wave per node: segmented softmax + reflected weighted aggregation (bf16 Q)
__global__ void k_agg(const int* __restrict__ rs, const int* __restrict__ adj_col,
                      const int* __restrict__ rel_ids, const float* __restrict__ rel_vals,
                      const unsigned char* __restrict__ flag, const float* __restrict__ tp,
                      const float* __restrict__ ss_rel, const float* __restrict__ att_n,
                      const float* __restrict__ att_t, const float* __restrict__ rel_emb,
                      const float* __restrict__ relW, short* __restrict__ Q,
                      int n, int layer){
  int wid = threadIdx.x>>6, lane = threadIdx.x&63;
  int node = blockIdx.x*4 + wid;
  if(node>=n) return;
  int s = rs[node], e = rs[node+1];
  float4 acc = make_float4(0.f,0.f,0.f,0.f);
  if(e > s){
    float mx = -INFINITY;
    for(int i=s+lane;i<e;i+=64){
      int rid = rel_ids[i]; float rv = rel_vals[i];
      float a = 0.f;
      if(rv>0.f){
        float t = tp[adj_col[i]];
        float sc = rv*rsqrtf(fmaxf(rv*rv*ss_rel[rid],1e-12f));
        a = t*sc*(flag[i]? att_t[rid] : att_n[rid]);
      }
      mx = fmaxf(mx,a);
    }
    mx = waveMax(mx);
    float se = 0.f;
    for(int i=s+lane;i<e;i+=64){
      int rid = rel_ids[i]; float rv = rel_vals[i];
      float a = 0.f;
      if(rv>0.f){
        float t = tp[adj_col[i]];
        float sc = rv*rsqrtf(fmaxf(rv*rv*ss_rel[rid],1e-12f));
        a = t*sc*(flag[i]? att_t[rid] : att_n[rid]);
      }
      se += expf(a-mx);
    }
    se = waveSum(se);
    float inv = 1.f/se;
    for(int i=s;i<e;i++){
      int rid = rel_ids[i]; float rv = rel_vals[i]; int col = adj_col[i];
      short4 nb4 = *(const short4*)(Q + (size_t)col*QSTR + layer*D + lane*4);
      float4 nb = make_float4(bf2f(nb4.x),bf2f(nb4.y),bf2f(nb4.z),bf2f(nb4.w));
      float w; float coef = 0.f; float4 rb = make_float4(0.f,0.f,0.f,0.f);
      if(rv>0.f){
        float t = tp[col];
        float sc = rv*rsqrtf(fmaxf(rv*rv*ss_rel[rid],1e-12f));
        const float* rp = (flag[i]? relW : rel_emb) + (size_t)rid*D;
        rb = *(const float4*)(rp + lane*4);
        float a = t*sc*(flag[i]? att_t[rid]:att_n[rid]);
        w = expf(a-mx)*inv;
        float dp = nb.x*rb.x+nb.y*rb.y+nb.z*rb.z+nb.w*rb.w;
        dp = waveSum(dp);
        coef = 2.f*t*t*sc*sc*dp;
      } else {
        w = expf(-mx)*inv;
      }
      acc.x += w*(nb.x - coef*rb.x);
      acc.y += w*(nb.y - coef*rb.y);
      acc.z += w*(nb.z - coef*rb.z);
      acc.w += w*(nb.w - coef*rb.w);
    }
  }
  float t = tp[node];
  short4 ob;
  ob.x=cvt_bf16(acc.x*t); ob.y=cvt_bf16(acc.y*t);
  ob.z=cvt_bf16(acc.z*t); ob.w=cvt_bf16(acc.w*t);
  *(short4*)(Q + (size_t)node*QSTR + (layer+1)*D + lane*4) = ob;
}

// l2-normalize proxy rows -> bf16 [128][768]
__global__ void k_proxynorm(const float* __restrict__ proxy, short* __restrict__ pn){
  __shared__ float sm[4];
  int j = blockIdx.x;
  float ssum=0.f;
  for(int d=threadIdx.x; d<DCAT; d+=256){ float v=proxy[(size_t)j*DCAT+d]; ssum+=v*v; }
  int lane=threadIdx.x&63, wid=threadIdx.x>>6;
  ssum = waveSum(ssum);
  if(lane==0) sm[wid]=ssum;
  __syncthreads();
  float scale = rsqrtf(fmaxf(sm[0]+sm[1]+sm[2]+sm[3],1e-12f));
  for(int d=threadIdx.x; d<DCAT; d+=256)
    pn[(size_t)j*DCAT + d] = cvt_bf16(proxy[(size_t)j*DCAT+d]*scale);
}

__global__ void k_cast(const float* __restrict__ in, short* __restrict__ out, long total){
  long i = (long)blockIdx.x*blockDim.x+threadIdx.x;
  if(i<total) out[i]=cvt_bf16(in[i]);
}

// transpose-cast: fp32 in[R][C] -> bf16 out[cc*ldo + coff + rr] (* sign)
__global__ void k_tcast(const float* __restrict__ in, short* __restrict__ out,
                        int R, int C, int ldo, int coff, float sign){
  __shared__ float tile[32][33];
  int bx = blockIdx.x*32, by = blockIdx.y*32;
  for(int i=threadIdx.y;i<32;i+=8){
    int rr = by+i, cc = bx+threadIdx.x;
    if(rr<R && cc<C) tile[i][threadIdx.x] = in[(size_t)rr*C + cc];
  }
  __syncthreads();
  for(int i=threadIdx.y;i<32;i+=8){
    int cc = bx+i, rr = by+threadIdx.x;
    if(cc<C && rr<R) out[(size_t)cc*ldo + coff + rr] = cvt_bf16(sign*tile[threadIdx.x][i]);
  }
}

// per-row inverse l2 norm of Q cols 0..767
__global__ void k_sn(const short* __restrict__ Q, float* __restrict__ sn, int n){
  int wid=threadIdx.x>>6, lane=threadIdx.x&63;
  int row = blockIdx.x*4+wid; if(row>=n) return;
  const short* o = Q + (size_t)row*QSTR;
  float ss=0.f;
#pragma unroll
  for(int c=0;c<3;c++){
    short4 v = *(const short4*)(o + c*256 + lane*4);
    float a=bf2f(v.x),b=bf2f(v.y),cc=bf2f(v.z),d=bf2f(v.w);
    ss += a*a+b*b+cc*cc+d*d;
  }
  ss = waveSum(ss);
  if(lane==0) sn[row]=rsqrtf(fmaxf(ss,1e-12f));
}

// row softmax over 128 logits -> bf16 probs into Q cols 768..895
__global__ void k_sm128(const float* __restrict__ P, short* __restrict__ Q, int n){
  int wid=threadIdx.x>>6, lane=threadIdx.x&63;
  int row=blockIdx.x*4+wid; if(row>=n) return;
  const float* pr = P + (size_t)row*NPX;
  float a=pr[lane], b=pr[lane+64];
  float m = waveMax(fmaxf(a,b));
  float ea=__expf(a-m), eb=__expf(b-m);
  float s = waveSum(ea+eb);
  short* pb = Q + (size_t)row*QSTR + DCAT;
  pb[lane]=cvt_bf16(ea/s); pb[lane+64]=cvt_bf16(eb/s);
}

// ---------------- MFMA GEMM, ring-3 counted-vmcnt pipeline -------------------------
// C[M,NTOT] = A[M,KC](stride LDA_) @ Bt[NTOT,KC](stride LDB_)^T, 128x128 tile, 4 waves.
// V=0: outF = acc*sn[row]      (proxy-att logits, l2n deferred)
// V=1: outB = bf16(sigmoid(acc))                   (gate)
// V=2: outF = bf2f(auxQ) - (1-bf2f(auxG))*acc      (final output)
// V=3: outF = acc                                  (plain fp32)
template<int LDA_, int LDB_, int NTOT, int KC, int V>
__global__ __launch_bounds__(256,2) void k_gemm(
    const short* __restrict__ A, const short* __restrict__ Bt,
    const short* __restrict__ auxQ, const short* __restrict__ auxG,
    const float* __restrict__ sn,
    float* __restrict__ outF, short* __restrict__ outB, int M)
{
  __shared__ short smem[3][2][128*32];
  const int tid = threadIdx.x;
  const int lane = tid & 63, w = tid >> 6;
  const int wm = w >> 1, wn = w & 1;
  // bijective XCD swizzle (m204)
  const int gx = gridDim.x;
  int nwg = gx*gridDim.y;
  int orig = blockIdx.y*gx + blockIdx.x;
  int q = nwg>>3, rm = nwg&7, xcd = orig&7, lid = orig>>3;
  int wg = (xcd<rm ? xcd*(q+1) : rm*(q+1)+(xcd-rm)*q) + lid;
  const int bn = (wg%gx)*128, bm = (wg/gx)*128;

  const short* Ag = A  + (size_t)bm * LDA_;
  const short* Bg = Bt + (size_t)bn * LDB_;

  auto stage = [&](int buf, int k0){
#pragma unroll
    for(int c=0;c<2;++c){
      int u = c*256 + tid;
      int row = u >> 2, cb = (u & 3) * 8;
      __builtin_amdgcn_global_load_lds(
        (const __attribute__((address_space(1))) unsigned int*)(Ag + (size_t)row*LDA_ + k0 + cb),
        (__attribute__((address_space(3))) unsigned int*)&smem[buf][0][u*8], 16, 0, 0);
      __builtin_amdgcn_global_load_lds(
        (const __attribute__((address_space(1))) unsigned int*)(Bg + (size_t)row*LDB_ + k0 + cb),
        (__attribute__((address_space(3))) unsigned int*)&smem[buf][1][u*8], 16, 0, 0);
    }
  };

  f32x4 acc[4][4] = {};
  const int lr = lane & 15, kg = lane >> 4;
  constexpr int NT = KC / 32;

  stage(0, 0);
  stage(1, 32);
  for(int t=0; t<NT; ++t){
    // wait for buf t's 4 loads (leave the newer stage's 4 in flight)
    if(t+1 < NT) asm volatile("s_waitcnt vmcnt(4)" ::: "memory");
    else         asm volatile("s_waitcnt vmcnt(0)" ::: "memory");
    __builtin_amdgcn_s_barrier();
    __builtin_amdgcn_sched_barrier(0);
    if(t+2 < NT) stage((t+2)%3, (t+2)*32);
    const short* Al = &smem[t%3][0][0];
    const short* Bl = &smem[t%3][1][0];
    bf16x8 af[4], bfr[4];
#pragma unroll
    for(int i=0;i<4;++i)
      af[i] = *(const bf16x8*)(Al + (wm*64 + i*16 + lr)*32 + kg*8);
#pragma unroll
    for(int j=0;j<4;++j)
      bfr[j] = *(const bf16x8*)(Bl + (wn*64 + j*16 + lr)*32 + kg*8);
#pragma unroll
    for(int i=0;i<4;++i)
#pragma unroll
      for(int j=0;j<4;++j)
        acc[i][j] = __builtin_amdgcn_mfma_f32_16x16x32_bf16(af[i], bfr[j], acc[i][j], 0, 0, 0);
  }

  const int row0 = bm + wm*64 + (lane>>4)*4;
  const int col0 = bn + wn*64 + lr;
#pragma unroll
  for(int i=0;i<4;++i){
#pragma unroll
    for(int j=0;j<4;++j){
      int col = col0 + j*16;
#pragma unroll
      for(int r=0;r<4;++r){
        int row = row0 + i*16 + r;
        if(row < M){
          float v = acc[i][j][r];
          if constexpr (V == 0){
            outF[(size_t)row*NTOT + col] = v * sn[row];
          } else if constexpr (V == 1){
            outB[(size_t)row*NTOT + col] = cvt_bf16(1.f/(1.f+__expf(-v)));
          } else if constexpr (V == 2){
            float oc = bf2f(auxQ[(size_t)row*QSTR + col]);
            float g  = bf2f(auxG[(size_t)row*DCAT + col]);
            outF[(size_t)row*NTOT + col] = oc - (1.f-g)*v;
          } else {
            outF[(size_t)row*NTOT + col] = v;
          }
        }
      }
    }
  }
}

__global__ void k_copyp(const float* __restrict__ p, float* __restrict__ out, int n){
  int i = blockIdx.x*blockDim.x+threadIdx.x;
  if(i<n) out[i]=p[i];
}

extern "C" void kernel_launch(void* const* d_in, const int* in_sizes, int n_in,
                              void* d_out, int out_size, void* d_ws, size_t ws_size,
                              hipStream_t stream){
  const float* features = (const float*)d_in[0];
  const float* rel_emb  = (const float*)d_in[1];
  const float* p        = (const float*)d_in[2];
  const float* w_keys   = (const float*)d_in[3];
  const float* attn     = (const float*)d_in[4];
  const float* proxy    = (const float*)d_in[5];
  const float* gatek    = (const float*)d_in[6];
  const float* rel_vals = (const float*)d_in[7];
  const int* adj_row    = (const int*)d_in[8];
  const int* adj_col    = (const int*)d_in[9];
  const int* rel_ids    = (const int*)d_in[10];
  const int* new_idx    = (const int*)d_in[11];

  const int n    = in_sizes[2];
  const int r    = in_sizes[1]/D;
  const int e    = in_sizes[7];
  const int ksel = in_sizes[11];
  const size_t Mpad = ((size_t)n + 127) & ~(size_t)127;

  char* ws = (char*)d_ws;
  size_t off=0;
  auto alloc=[&](size_t bytes)->void*{ void* pp = ws+off; off=(off+bytes+255)&~(size_t)255; return pp; };
  float* tp      = (float*)alloc((size_t)n*4);
  int*   rs      = (int*)alloc((size_t)(n+1)*4);
  unsigned char* flag = (unsigned char*)alloc((size_t)e);
  float* ss_rel  = (float*)alloc((size_t)r*4);
  float* att_n   = (float*)alloc((size_t)2*r*4);
  float* att_t   = (float*)alloc((size_t)2*r*4);
  float* relW    = (float*)alloc((size_t)2*r*D*4);
  short* pn      = (short*)alloc((size_t)NPX*DCAT*2);    // l2n(proxy) bf16 [128,768]
  short* proxyb  = (short*)alloc((size_t)NPX*DCAT*2);    // proxy bf16
  short* Bt2     = (short*)alloc((size_t)DCAT*NPX*2);    // proxy^T bf16 [768,128]
  short* BG      = (short*)alloc((size_t)DCAT*QSTR*2);   // [gk^T | -(proxy@gk)^T] [768,896]
  float* MxF     = (float*)alloc((size_t)NPX*DCAT*4);    // proxy@gk fp32
  float* sn      = (float*)alloc(Mpad*4);
  float* P       = (float*)alloc(Mpad*NPX*4);            // proxy-att logits fp32
  short* gbuf    = (short*)alloc(Mpad*DCAT*2);           // gate bf16
  short* Q       = (short*)alloc(Mpad*QSTR*2);           // [outcat | probs] bf16

  float* outF = (float*)d_out;
  float* pout = (float*)d_out + (size_t)n*DCAT;

  hipMemsetAsync(flag, 0, (size_t)e, stream);
  hipMemsetAsync(Q + (size_t)n*QSTR, 0, (Mpad-(size_t)n)*QSTR*2, stream);

  k_tanh<<<(n+255)/256,256,0,stream>>>(p,tp,n);
  k_rowstart<<<(n+256)/256,256,0,stream>>>(adj_row,rs,n,e);
  k_flag<<<(ksel+255)/256,256,0,stream>>>(new_idx,flag,ksel);
  k_relprep<<<r,256,0,stream>>>(rel_emb,attn,ss_rel,att_n,r);
  for(int l=0;l<2;l++)
    k_relW<<<r,256,0,stream>>>(rel_emb, w_keys+(size_t)l*D*D, attn+(size_t)l*D,
                               relW+(size_t)l*r*D, att_t+(size_t)l*r, r);
  k_proxynorm<<<NPX,256,0,stream>>>(proxy,pn);
  {
    long tpx = (long)NPX*DCAT;
    k_cast<<<(int)((tpx+255)/256),256,0,stream>>>(proxy, proxyb, tpx);
    dim3 tb(32,8);
    // BG cols 0..767 = gk^T
    k_tcast<<<dim3(DCAT/32, DCAT/32), tb, 0, stream>>>(gatek, BG, DCAT, DCAT, QSTR, 0, 1.f);
    // Mx = proxy @ gk  [128,768]
    k_gemm<DCAT, QSTR, DCAT, DCAT, 3><<<dim3(DCAT/128,1),256,0,stream>>>(
        proxyb, BG, nullptr, nullptr, nullptr, MxF, nullptr, NPX);
    // BG cols 768..895 = -Mx^T
    k_tcast<<<dim3(DCAT/32, NPX/32), tb, 0, stream>>>(MxF, BG, NPX, DCAT, QSTR, DCAT, -1.f);
    // Bt2 = proxy^T [768,128]
    k_tcast<<<dim3(DCAT/32, NPX/32), tb, 0, stream>>>(proxy, Bt2, NPX, DCAT, NPX, 0, 1.f);
  }
  long tot0 = (long)n*D;
  k_init0<<<(int)((tot0+255)/256),256,0,stream>>>(features,tp,Q,tot0);
  for(int l=0;l<2;l++)
    k_agg<<<(n+3)/4,256,0,stream>>>(rs,adj_col,rel_ids,rel_vals,flag,tp,ss_rel,
                                    att_n+(size_t)l*r, att_t+(size_t)l*r, rel_emb,
                                    relW+(size_t)l*r*D, Q, n, l);
  k_sn<<<(n+3)/4,256,0,stream>>>(Q,sn,n);

  int mt = (int)(Mpad/128);
  // GEMM-1: P = (Q[:, :768] @ pn^T) * sn[row]   [M,128], K=768
  k_gemm<QSTR, DCAT, NPX, DCAT, 0><<<dim3(1, mt),256,0,stream>>>(
      Q, pn, nullptr, nullptr, sn, P, nullptr, n);
  k_sm128<<<(n+3)/4,256,0,stream>>>(P,Q,n);
  // kG: gate = sigmoid(Q[:, :896] @ BG^T)   [M,768], K=896
  k_gemm<QSTR, QSTR, DCAT, QSTR, 1><<<dim3(DCAT/128, mt),256,0,stream>>>(
      Q, BG, nullptr, nullptr, nullptr, nullptr, gbuf, n);
  // kO: out = bf2f(Q) - (1-g)*(Pb @ Bt2^T)   [M,768], K=128
  k_gemm<QSTR, NPX, DCAT, NPX, 2><<<dim3(DCAT/128, mt),256,0,stream>>>(
      Q+DCAT, Bt2, Q, gbuf, nullptr, outF, nullptr, n);
  k_copyp<<<(n+255)/256,256,0,stream>>>(p,pout,n);
}

// Round 5
// 563.424 us; speedup vs baseline: 1.1683x; 1.0555x over previous
//
#include <hip/hip_runtime.h>
#include <math.h>

#define D 256
#define DCAT 768
#define NPX 128
#define QSTR 896   // Q row stride: [outcat(768) | P(128)] bf16

typedef __attribute__((ext_vector_type(8))) short bf16x8;
typedef __attribute__((ext_vector_type(4))) float f32x4;

__device__ __forceinline__ short cvt_bf16(float f){
  union { float f; unsigned u; } v; v.f = f;
  unsigned r = v.u + 0x7FFF + ((v.u >> 16) & 1);   // RNE
  return (short)(r >> 16);
}
__device__ __forceinline__ float bf2f(short s){
  union { float f; unsigned u; } v; v.u = ((unsigned)(unsigned short)s) << 16;
  return v.f;
}

__device__ __forceinline__ float waveSum(float v){
#pragma unroll
  for(int o=32;o>=1;o>>=1) v += __shfl_xor(v,o,64);
  return v;
}
__device__ __forceinline__ float waveMax(float v){
#pragma unroll
  for(int o=32;o>=1;o>>=1) v = fmaxf(v,__shfl_xor(v,o,64));
  return v;
}

__global__ void k_tanh(const float* __restrict__ p, float* __restrict__ tp, int n){
  int i = blockIdx.x*blockDim.x+threadIdx.x;
  if(i<n) tp[i]=tanhf(p[i]);
}

__global__ void k_rowstart(const int* __restrict__ adj_row, int* __restrict__ rs, int n, int e){
  int i = blockIdx.x*blockDim.x+threadIdx.x;
  if(i>n) return;
  int lo=0, hi=e;
  while(lo<hi){ int mid=(lo+hi)>>1; if(adj_row[mid]<i) lo=mid+1; else hi=mid; }
  rs[i]=lo;
}

__global__ void k_flag(const int* __restrict__ idx, unsigned char* __restrict__ flag, int k){
  int i = blockIdx.x*blockDim.x+threadIdx.x;
  if(i<k) flag[idx[i]] = 1;
}

__global__ void k_relprep(const float* __restrict__ rel_emb, const float* __restrict__ attn,
                          float* __restrict__ ss_rel, float* __restrict__ att_n, int R_){
  __shared__ float sm[4];
  int r = blockIdx.x; int d = threadIdx.x;
  float v = rel_emb[(size_t)r*D+d];
  int lane=threadIdx.x&63, wid=threadIdx.x>>6;
  float s = waveSum(v*v);
  if(lane==0) sm[wid]=s;
  __syncthreads();
  if(threadIdx.x==0) ss_rel[r]=sm[0]+sm[1]+sm[2]+sm[3];
  __syncthreads();
  for(int l=0;l<2;l++){
    float dd = waveSum(v*attn[l*D+d]);
    if(lane==0) sm[wid]=dd;
    __syncthreads();
    if(threadIdx.x==0) att_n[(size_t)l*R_+r]=sm[0]+sm[1]+sm[2]+sm[3];
    __syncthreads();
  }
}

// per-relation: rel_emb_row @ W -> bf16 table (and fp32 dot with attn kernel)
__global__ void k_relW(const float* __restrict__ rel_emb, const float* __restrict__ W,
                       const float* __restrict__ ak, short* __restrict__ rwb,
                       float* __restrict__ att_t, int R_){
  __shared__ float sm[4];
  int r=blockIdx.x, d=threadIdx.x;
  const float* row = rel_emb + (size_t)r*D;
  float acc=0.f;
#pragma unroll 4
  for(int k=0;k<D;k++) acc = fmaf(row[k], W[(size_t)k*D+d], acc);
  rwb[(size_t)r*D+d]=cvt_bf16(acc);
  int lane=threadIdx.x&63, wid=threadIdx.x>>6;
  float dd = waveSum(acc*ak[d]);
  if(lane==0) sm[wid]=dd;
  __syncthreads();
  if(threadIdx.x==0) att_t[r]=sm[0]+sm[1]+sm[2]+sm[3];
}

__global__ void k_init0(const float* __restrict__ features, const float* __restrict__ tp,
                        short* __restrict__ Q, long total){
  long i = (long)blockIdx.x*blockDim.x+threadIdx.x;
  if(i >= total) return;
  int row = (int)(i>>8), d = (int)(i&255);
  Q[(size_t)row*QSTR + d] = cvt_bf16(features[i]*tp[row]);
}

// one wave per node; main loop quarter-wave-parallel (4 edges in flight)
__global__ void k_agg(const int* __restrict__ rs, const int* __restrict__ adj_col,
                      const int* __restrict__ rel_ids, const float* __restrict__ rel_vals,
                      const unsigned char* __restrict__ flag, const float* __restrict__ tp,
                      const float* __restrict__ ss_rel, const float* __restrict__ att_n,
                      const float* __restrict__ att_t, const short* __restrict__ reb,
                      const short* __restrict__ rwb, short* __restrict__ Q,
                      int n, int layer){
  int wid = threadIdx.x>>6, lane = threadIdx.x&63;
  int node = blockIdx.x*4 + wid;
  if(node>=n) return;
  int s = rs[node], e = rs[node+1];
  float accq[16];
#pragma unroll
  for(int k=0;k<16;k++) accq[k]=0.f;
  if(e > s){
    float mx = -INFINITY;
    for(int i=s+lane;i<e;i+=64){
      int rid = rel_ids[i]; float rv = rel_vals[i];
      float a = 0.f;
      if(rv>0.f){
        float t = tp[adj_col[i]];
        float sc = rv*rsqrtf(fmaxf(rv*rv*ss_rel[rid],1e-12f));
        a = t*sc*(flag[i]? att_t[rid] : att_n[rid]);
      }
      mx = fmaxf(mx,a);
    }
    mx = waveMax(mx);
    float se = 0.f;
    for(int i=s+lane;i<e;i+=64){
      int rid = rel_ids[i]; float rv = rel_vals[i];
      float a = 0.f;
      if(rv>0.f){
        float t = tp[adj_col[i]];
        float sc = rv*rsqrtf(fmaxf(rv*rv*ss_rel[rid],1e-12f));
        a = t*sc*(flag[i]? att_t[rid] : att_n[rid]);
      }
      se += __expf(a-mx);
    }
    se = waveSum(se);
    float inv = 1.f/se;
    int qid = lane>>4, ql = lane&15;
    for(int i0=s; i0<e; i0+=4){
      int j = i0 + qid;
      float w=0.f, coef=0.f;
      float nbv[16], rbv[16];
#pragma unroll
      for(int k=0;k<16;k++){ nbv[k]=0.f; rbv[k]=0.f; }
      if(j < e){
        int rid = rel_ids[j]; float rv = rel_vals[j]; int col = adj_col[j];
        const short* np = Q + (size_t)col*QSTR + layer*D + ql*16;
        bf16x8 n0 = *(const bf16x8*)np;
        bf16x8 n1 = *(const bf16x8*)(np+8);
#pragma unroll
        for(int k=0;k<8;k++){ nbv[k]=bf2f(n0[k]); nbv[k+8]=bf2f(n1[k]); }
        if(rv>0.f){
          float t = tp[col];
          float sc = rv*rsqrtf(fmaxf(rv*rv*ss_rel[rid],1e-12f));
          bool f = flag[j];
          const short* rp = (f? rwb : reb) + (size_t)rid*D + ql*16;
          bf16x8 r0 = *(const bf16x8*)rp;
          bf16x8 r1 = *(const bf16x8*)(rp+8);
#pragma unroll
          for(int k=0;k<8;k++){ rbv[k]=bf2f(r0[k]); rbv[k+8]=bf2f(r1[k]); }
          float dp = 0.f;
#pragma unroll
          for(int k=0;k<16;k++) dp += nbv[k]*rbv[k];
#pragma unroll
          for(int o=1;o<16;o<<=1) dp += __shfl_xor(dp,o,64);
          float a = t*sc*(f? att_t[rid] : att_n[rid]);
          w = __expf(a-mx)*inv;
          coef = 2.f*t*t*sc*sc*dp;
        } else {
          w = __expf(-mx)*inv;
        }
      }
#pragma unroll
      for(int k=0;k<16;k++) accq[k] += w*(nbv[k] - coef*rbv[k]);
    }
  }
  // combine quarters
#pragma unroll
  for(int k=0;k<16;k++){
    float v = accq[k];
    v += __shfl_xor(v,16,64);
    v += __shfl_xor(v,32,64);
    accq[k] = v;
  }
  if((lane>>4)==0){
    float t0 = tp[node];
    bf16x8 o0, o1;
#pragma unroll
    for(int k=0;k<8;k++){ o0[k]=cvt_bf16(accq[k]*t0); o1[k]=cvt_bf16(accq[k+8]*t0); }
    short* op = Q + (size_t)node*QSTR + (layer+1)*D + (lane&15)*16;
    *(bf16x8*)op = o0;
    *(bf16x8*)(op+8) = o1;
  }
}

// l2-normalize proxy rows -> bf16 [128][768]
__global__ void k_proxynorm(const float* __restrict__ proxy, short* __restrict__ pn){
  __shared__ float sm[4];
  int j = blockIdx.x;
  float ssum=0.f;
  for(int d=threadIdx.x; d<DCAT; d+=256){ float v=proxy[(size_t)j*DCAT+d]; ssum+=v*v; }
  int lane=threadIdx.x&63, wid=threadIdx.x>>6;
  ssum = waveSum(ssum);
  if(lane==0) sm[wid]=ssum;
  __syncthreads();
  float scale = rsqrtf(fmaxf(sm[0]+sm[1]+sm[2]+sm[3],1e-12f));
  for(int d=threadIdx.x; d<DCAT; d+=256)
    pn[(size_t)j*DCAT + d] = cvt_bf16(proxy[(size_t)j*DCAT+d]*scale);
}

__global__ void k_cast(const float* __restrict__ in, short* __restrict__ out, long total){
  long i = (long)blockIdx.x*blockDim.x+threadIdx.x;
  if(i<total) out[i]=cvt_bf16(in[i]);
}

// transpose-cast: fp32 in[R][C] -> bf16 out[cc*ldo + coff + rr] (* sign)
__global__ void k_tcast(const float* __restrict__ in, short* __restrict__ out,
                        int R, int C, int ldo, int coff, float sign){
  __shared__ float tile[32][33];
  int bx = blockIdx.x*32, by = blockIdx.y*32;
  for(int i=threadIdx.y;i<32;i+=8){
    int rr = by+i, cc = bx+threadIdx.x;
    if(rr<R && cc<C) tile[i][threadIdx.x] = in[(size_t)rr*C + cc];
  }
  __syncthreads();
  for(int i=threadIdx.y;i<32;i+=8){
    int cc = bx+i, rr = by+threadIdx.x;
    if(cc<C && rr<R) out[(size_t)cc*ldo + coff + rr] = cvt_bf16(sign*tile[threadIdx.x][i]);
  }
}

// per-row inverse l2 norm of Q cols 0..767
__global__ void k_sn(const short* __restrict__ Q, float* __restrict__ sn, int n){
  int wid=threadIdx.x>>6, lane=threadIdx.x&63;
  int row = blockIdx.x*4+wid; if(row>=n) return;
  const short* o = Q + (size_t)row*QSTR;
  float ss=0.f;
#pragma unroll
  for(int c=0;c<3;c++){
    short4 v = *(const short4*)(o + c*256 + lane*4);
    float a=bf2f(v.x),b=bf2f(v.y),cc=bf2f(v.z),d=bf2f(v.w);
    ss += a*a+b*b+cc*cc+d*d;
  }
  ss = waveSum(ss);
  if(lane==0) sn[row]=rsqrtf(fmaxf(ss,1e-12f));
}

// row softmax over 128 logits -> bf16 probs into Q cols 768..895
__global__ void k_sm128(const float* __restrict__ P, short* __restrict__ Q, int n){
  int wid=threadIdx.x>>6, lane=threadIdx.x&63;
  int row=blockIdx.x*4+wid; if(row>=n) return;
  const float* pr = P + (size_t)row*NPX;
  float a=pr[lane], b=pr[lane+64];
  float m = waveMax(fmaxf(a,b));
  float ea=__expf(a-m), eb=__expf(b-m);
  float s = waveSum(ea+eb);
  short* pb = Q + (size_t)row*QSTR + DCAT;
  pb[lane]=cvt_bf16(ea/s); pb[lane+64]=cvt_bf16(eb/s);
}

// ---------------- MFMA GEMM, ring-3 counted-vmcnt pipeline -------------------------
// V=0: outF = acc*sn[row]   V=1: outB = bf16(sigmoid(acc))   V=3: outF = acc
template<int LDA_, int LDB_, int NTOT, int KC, int V>
__global__ __launch_bounds__(256,2) void k_gemm(
    const short* __restrict__ A, const short* __restrict__ Bt,
    const float* __restrict__ sn,
    float* __restrict__ outF, short* __restrict__ outB, int M)
{
  __shared__ short smem[3][2][128*32];
  const int tid = threadIdx.x;
  const int lane = tid & 63, w = tid >> 6;
  const int wm = w >> 1, wn = w & 1;
  const int gx = gridDim.x;
  int nwg = gx*gridDim.y;
  int orig = blockIdx.y*gx + blockIdx.x;
  int q = nwg>>3, rm = nwg&7, xcd = orig&7, lid = orig>>3;
  int wg = (xcd<rm ? xcd*(q+1) : rm*(q+1)+(xcd-rm)*q) + lid;
  const int bn = (wg%gx)*128, bm = (wg/gx)*128;

  const short* Ag = A  + (size_t)bm * LDA_;
  const short* Bg = Bt + (size_t)bn * LDB_;

  auto stage = [&](int buf, int k0){
#pragma unroll
    for(int c=0;c<2;++c){
      int u = c*256 + tid;
      int row = u >> 2, cb = (u & 3) * 8;
      __builtin_amdgcn_global_load_lds(
        (const __attribute__((address_space(1))) unsigned int*)(Ag + (size_t)row*LDA_ + k0 + cb),
        (__attribute__((address_space(3))) unsigned int*)&smem[buf][0][u*8], 16, 0, 0);
      __builtin_amdgcn_global_load_lds(
        (const __attribute__((address_space(1))) unsigned int*)(Bg + (size_t)row*LDB_ + k0 + cb),
        (__attribute__((address_space(3))) unsigned int*)&smem[buf][1][u*8], 16, 0, 0);
    }
  };

  f32x4 acc[4][4] = {};
  const int lr = lane & 15, kg = lane >> 4;
  constexpr int NT = KC / 32;

  stage(0, 0);
  stage(1, 32);
  for(int t=0; t<NT; ++t){
    if(t+1 < NT) asm volatile("s_waitcnt vmcnt(4)" ::: "memory");
    else         asm volatile("s_waitcnt vmcnt(0)" ::: "memory");
    __builtin_amdgcn_s_barrier();
    __builtin_amdgcn_sched_barrier(0);
    if(t+2 < NT) stage((t+2)%3, (t+2)*32);
    const short* Al = &smem[t%3][0][0];
    const short* Bl = &smem[t%3][1][0];
    bf16x8 af[4], bfr[4];
#pragma unroll
    for(int i=0;i<4;++i)
      af[i] = *(const bf16x8*)(Al + (wm*64 + i*16 + lr)*32 + kg*8);
#pragma unroll
    for(int j=0;j<4;++j)
      bfr[j] = *(const bf16x8*)(Bl + (wn*64 + j*16 + lr)*32 + kg*8);
#pragma unroll
    for(int i=0;i<4;++i)
#pragma unroll
      for(int j=0;j<4;++j)
        acc[i][j] = __builtin_amdgcn_mfma_f32_16x16x32_bf16(af[i], bfr[j], acc[i][j], 0, 0, 0);
  }

  const int row0 = bm + wm*64 + (lane>>4)*4;
  const int col0 = bn + wn*64 + lr;
#pragma unroll
  for(int i=0;i<4;++i){
#pragma unroll
    for(int j=0;j<4;++j){
      int col = col0 + j*16;
#pragma unroll
      for(int r=0;r<4;++r){
        int row = row0 + i*16 + r;
        if(row < M){
          float v = acc[i][j][r];
          if constexpr (V == 0){
            outF[(size_t)row*NTOT + col] = v * sn[row];
          } else if constexpr (V == 1){
            outB[(size_t)row*NTOT + col] = cvt_bf16(1.f/(1.f+__expf(-v)));
          } else {
            outF[(size_t)row*NTOT + col] = v;
          }
        }
      }
    }
  }
}

// ---------------- k_out: out = oc - (1-g)*(P@proxy), K=128, no staging ------------
__global__ __launch_bounds__(256) void k_out(
    const short* __restrict__ Q, const short* __restrict__ Bt2,
    const short* __restrict__ gbuf, float* __restrict__ outF, int M)
{
  __shared__ short cst[128*128];
  const int tid = threadIdx.x, lane = tid&63, w = tid>>6;
  const int wm = w>>1, wn = w&1;
  const int gx = gridDim.x;
  int nwg = gx*gridDim.y;
  int orig = blockIdx.y*gx + blockIdx.x;
  int q8 = nwg>>3, rm = nwg&7, xcd = orig&7, lid = orig>>3;
  int wg = (xcd<rm ? xcd*(q8+1) : rm*(q8+1)+(xcd-rm)*q8) + lid;
  const int bn = (wg%gx)*128, bm = (wg/gx)*128;
  const int lr = lane&15, kg = lane>>4;

  f32x4 acc[4][4] = {};
#pragma unroll
  for(int ks=0; ks<4; ++ks){
    bf16x8 af[4], bb[4];
#pragma unroll
    for(int i=0;i<4;++i)
      af[i] = *(const bf16x8*)(Q + (size_t)(bm + wm*64 + i*16 + lr)*QSTR + DCAT + ks*32 + kg*8);
#pragma unroll
    for(int j=0;j<4;++j)
      bb[j] = *(const bf16x8*)(Bt2 + (size_t)(bn + wn*64 + j*16 + lr)*NPX + ks*32 + kg*8);
#pragma unroll
    for(int i=0;i<4;++i)
#pragma unroll
      for(int j=0;j<4;++j)
        acc[i][j] = __builtin_amdgcn_mfma_f32_16x16x32_bf16(af[i], bb[j], acc[i][j], 0, 0, 0);
  }
#pragma unroll
  for(int i=0;i<4;++i)
#pragma unroll
    for(int j=0;j<4;++j)
#pragma unroll
      for(int r2=0;r2<4;++r2)
        cst[(wm*64 + i*16 + kg*4 + r2)*128 + wn*64 + j*16 + lr] = cvt_bf16(acc[i][j][r2]);
  __syncthreads();
  const int rl0 = tid>>4, c0 = (tid&15)*8;
#pragma unroll
  for(int rr=0; rr<8; ++rr){
    int rl = rl0 + rr*16;
    int rg = bm + rl;
    if(rg >= M) continue;
    bf16x8 c8  = *(const bf16x8*)(cst + rl*128 + c0);
    bf16x8 oc8 = *(const bf16x8*)(Q + (size_t)rg*QSTR + bn + c0);
    bf16x8 g8  = *(const bf16x8*)(gbuf + (size_t)rg*DCAT + bn + c0);
    float ov[8];
#pragma unroll
    for(int k=0;k<8;k++){
      float g = bf2f(g8[k]);
      ov[k] = bf2f(oc8[k]) - (1.f-g)*bf2f(c8[k]);
    }
    *(float4*)(outF + (size_t)rg*DCAT + bn + c0)     = make_float4(ov[0],ov[1],ov[2],ov[3]);
    *(float4*)(outF + (size_t)rg*DCAT + bn + c0 + 4) = make_float4(ov[4],ov[5],ov[6],ov[7]);
  }
}

__global__ void k_copyp(const float* __restrict__ p, float* __restrict__ out, int n){
  int i = blockIdx.x*blockDim.x+threadIdx.x;
  if(i<n) out[i]=p[i];
}

extern "C" void kernel_launch(void* const* d_in, const int* in_sizes, int n_in,
                              void* d_out, int out_size, void* d_ws, size_t ws_size,
                              hipStream_t stream){
  const float* features = (const float*)d_in[0];
  const float* rel_emb  = (const float*)d_in[1];
  const float* p        = (const float*)d_in[2];
  const float* w_keys   = (const float*)d_in[3];
  const float* attn     = (const float*)d_in[4];
  const float* proxy    = (const float*)d_in[5];
  const float* gatek    = (const float*)d_in[6];
  const float* rel_vals = (const float*)d_in[7];
  const int* adj_row    = (const int*)d_in[8];
  const int* adj_col    = (const int*)d_in[9];
  const int* rel_ids    = (const int*)d_in[10];
  const int* new_idx    = (const int*)d_in[11];

  const int n    = in_sizes[2];
  const int r    = in_sizes[1]/D;
  const int e    = in_sizes[7];
  const int ksel = in_sizes[11];
  const size_t Mpad = ((size_t)n + 127) & ~(size_t)127;

  char* ws = (char*)d_ws;
  size_t off=0;
  auto alloc=[&](size_t bytes)->void*{ void* pp = ws+off; off=(off+bytes+255)&~(size_t)255; return pp; };
  float* tp      = (float*)alloc((size_t)n*4);
  int*   rs      = (int*)alloc((size_t)(n+1)*4);
  unsigned char* flag = (unsigned char*)alloc((size_t)e);
  float* ss_rel  = (float*)alloc((size_t)r*4);
  float* att_n   = (float*)alloc((size_t)2*r*4);
  float* att_t   = (float*)alloc((size_t)2*r*4);
  short* reb     = (short*)alloc((size_t)r*D*2);         // rel_emb bf16
  short* rwb     = (short*)alloc((size_t)2*r*D*2);       // relW bf16 (2 layers)
  short* pn      = (short*)alloc((size_t)NPX*DCAT*2);    // l2n(proxy) bf16 [128,768]
  short* proxyb  = (short*)alloc((size_t)NPX*DCAT*2);    // proxy bf16
  short* Bt2     = (short*)alloc((size_t)DCAT*NPX*2);    // proxy^T bf16 [768,128]
  short* BG      = (short*)alloc((size_t)DCAT*QSTR*2);   // [gk^T | -(proxy@gk)^T] [768,896]
  float* MxF     = (float*)alloc((size_t)NPX*DCAT*4);    // proxy@gk fp32
  float* sn      = (float*)alloc(Mpad*4);
  float* P       = (float*)alloc(Mpad*NPX*4);            // proxy-att logits fp32
  short* gbuf    = (short*)alloc(Mpad*DCAT*2);           // gate bf16
  short* Q       = (short*)alloc(Mpad*QSTR*2);           // [outcat | probs] bf16

  float* outF = (float*)d_out;
  float* pout = (float*)d_out + (size_t)n*DCAT;

  hipMemsetAsync(flag, 0, (size_t)e, stream);
  hipMemsetAsync(Q + (size_t)n*QSTR, 0, (Mpad-(size_t)n)*QSTR*2, stream);

  k_tanh<<<(n+255)/256,256,0,stream>>>(p,tp,n);
  k_rowstart<<<(n+256)/256,256,0,stream>>>(adj_row,rs,n,e);
  k_flag<<<(ksel+255)/256,256,0,stream>>>(new_idx,flag,ksel);
  k_relprep<<<r,256,0,stream>>>(rel_emb,attn,ss_rel,att_n,r);
  {
    long tre = (long)r*D;
    k_cast<<<(int)((tre+255)/256),256,0,stream>>>(rel_emb, reb, tre);
  }
  for(int l=0;l<2;l++)
    k_relW<<<r,256,0,stream>>>(rel_emb, w_keys+(size_t)l*D*D, attn+(size_t)l*D,
                               rwb+(size_t)l*r*D, att_t+(size_t)l*r, r);
  k_proxynorm<<<NPX,256,0,stream>>>(proxy,pn);
  {
    long tpx = (long)NPX*DCAT;
    k_cast<<<(int)((tpx+255)/256),256,0,stream>>>(proxy, proxyb, tpx);
    dim3 tb(32,8);
    k_tcast<<<dim3(DCAT/32, DCAT/32), tb, 0, stream>>>(gatek, BG, DCAT, DCAT, QSTR, 0, 1.f);
    k_gemm<DCAT, QSTR, DCAT, DCAT, 3><<<dim3(DCAT/128,1),256,0,stream>>>(
        proxyb, BG, nullptr, MxF, nullptr, NPX);
    k_tcast<<<dim3(DCAT/32, NPX/32), tb, 0, stream>>>(MxF, BG, NPX, DCAT, QSTR, DCAT, -1.f);
    k_tcast<<<dim3(DCAT/32, NPX/32), tb, 0, stream>>>(proxy, Bt2, NPX, DCAT, NPX, 0, 1.f);
  }
  long tot0 = (long)n*D;
  k_init0<<<(int)((tot0+255)/256),256,0,stream>>>(features,tp,Q,tot0);
  for(int l=0;l<2;l++)
    k_agg<<<(n+3)/4,256,0,stream>>>(rs,adj_col,rel_ids,rel_vals,flag,tp,ss_rel,
                                    att_n+(size_t)l*r, att_t+(size_t)l*r, reb,
                                    rwb+(size_t)l*r*D, Q, n, l);
  k_sn<<<(n+3)/4,256,0,stream>>>(Q,sn,n);

  int mt = (int)(Mpad/128);
  // GEMM-1: P = (Q[:, :768] @ pn^T) * sn[row]   [M,128], K=768
  k_gemm<QSTR, DCAT, NPX, DCAT, 0><<<dim3(1, mt),256,0,stream>>>(
      Q, pn, sn, P, nullptr, n);
  k_sm128<<<(n+3)/4,256,0,stream>>>(P,Q,n);
  // kG: gate = sigmoid(Q[:, :896] @ BG^T)   [M,768], K=896
  k_gemm<QSTR, QSTR, DCAT, QSTR, 1><<<dim3(DCAT/128, mt),256,0,stream>>>(
      Q, BG, nullptr, nullptr, gbuf, n);
  // k_out: out = oc - (1-g)*(P@proxy)   [M,768], K=128
  k_out<<<dim3(DCAT/128, mt),256,0,stream>>>(Q, Bt2, gbuf, outF, n);
  k_copyp<<<(n+255)/256,256,0,stream>>>(p,pout,n);
}

// Round 6
// 557.613 us; speedup vs baseline: 1.1805x; 1.0104x over previous
//
#include <hip/hip_runtime.h>
#include <math.h>

#define D 256
#define DCAT 768
#define NPX 128
#define QSTR 896   // Q row stride: [outcat(768) | P(128)] bf16

typedef __attribute__((ext_vector_type(8))) short bf16x8;
typedef __attribute__((ext_vector_type(4))) float f32x4;

__device__ __forceinline__ short cvt_bf16(float f){
  union { float f; unsigned u; } v; v.f = f;
  unsigned r = v.u + 0x7FFF + ((v.u >> 16) & 1);   // RNE
  return (short)(r >> 16);
}
__device__ __forceinline__ float bf2f(short s){
  union { float f; unsigned u; } v; v.u = ((unsigned)(unsigned short)s) << 16;
  return v.f;
}

__device__ __forceinline__ float waveSum(float v){
#pragma unroll
  for(int o=32;o>=1;o>>=1) v += __shfl_xor(v,o,64);
  return v;
}
__device__ __forceinline__ float waveMax(float v){
#pragma unroll
  for(int o=32;o>=1;o>>=1) v = fmaxf(v,__shfl_xor(v,o,64));
  return v;
}

__global__ void k_tanh(const float* __restrict__ p, float* __restrict__ tp, int n){
  int i = blockIdx.x*blockDim.x+threadIdx.x;
  if(i<n) tp[i]=tanhf(p[i]);
}

__global__ void k_rowstart(const int* __restrict__ adj_row, int* __restrict__ rs, int n, int e){
  int i = blockIdx.x*blockDim.x+threadIdx.x;
  if(i>n) return;
  int lo=0, hi=e;
  while(lo<hi){ int mid=(lo+hi)>>1; if(adj_row[mid]<i) lo=mid+1; else hi=mid; }
  rs[i]=lo;
}

__global__ void k_flag(const int* __restrict__ idx, unsigned char* __restrict__ flag, int k){
  int i = blockIdx.x*blockDim.x+threadIdx.x;
  if(i<k) flag[idx[i]] = 1;
}

__global__ void k_relprep(const float* __restrict__ rel_emb, const float* __restrict__ attn,
                          float* __restrict__ ss_rel, float* __restrict__ att_n, int R_){
  __shared__ float sm[4];
  int r = blockIdx.x; int d = threadIdx.x;
  float v = rel_emb[(size_t)r*D+d];
  int lane=threadIdx.x&63, wid=threadIdx.x>>6;
  float s = waveSum(v*v);
  if(lane==0) sm[wid]=s;
  __syncthreads();
  if(threadIdx.x==0) ss_rel[r]=sm[0]+sm[1]+sm[2]+sm[3];
  __syncthreads();
  for(int l=0;l<2;l++){
    float dd = waveSum(v*attn[l*D+d]);
    if(lane==0) sm[wid]=dd;
    __syncthreads();
    if(threadIdx.x==0) att_n[(size_t)l*R_+r]=sm[0]+sm[1]+sm[2]+sm[3];
    __syncthreads();
  }
}

// per-relation: rel_emb_row @ W -> bf16 table (and fp32 dot with attn kernel)
__global__ void k_relW(const float* __restrict__ rel_emb, const float* __restrict__ W,
                       const float* __restrict__ ak, short* __restrict__ rwb,
                       float* __restrict__ att_t, int R_){
  __shared__ float sm[4];
  int r=blockIdx.x, d=threadIdx.x;
  const float* row = rel_emb + (size_t)r*D;
  float acc=0.f;
#pragma unroll 4
  for(int k=0;k<D;k++) acc = fmaf(row[k], W[(size_t)k*D+d], acc);
  rwb[(size_t)r*D+d]=cvt_bf16(acc);
  int lane=threadIdx.x&63, wid=threadIdx.x>>6;
  float dd = waveSum(acc*ak[d]);
  if(lane==0) sm[wid]=dd;
  __syncthreads();
  if(threadIdx.x==0) att_t[r]=sm[0]+sm[1]+sm[2]+sm[3];
}

__global__ void k_init0(const float* __restrict__ features, const float* __restrict__ tp,
                        short* __restrict__ Q, long total){
  long i = (long)blockIdx.x*blockDim.x+threadIdx.x;
  if(i >= total) return;
  int row = (int)(i>>8), d = (int)(i&255);
  Q[(size_t)row*QSTR + d] = cvt_bf16(features[i]*tp[row]);
}

// one wave per node; main loop quarter-wave-parallel (4 edges in flight)
__global__ void k_agg(const int* __restrict__ rs, const int* __restrict__ adj_col,
                      const int* __restrict__ rel_ids, const float* __restrict__ rel_vals,
                      const unsigned char* __restrict__ flag, const float* __restrict__ tp,
                      const float* __restrict__ ss_rel, const float* __restrict__ att_n,
                      const float* __restrict__ att_t, const short* __restrict__ reb,
                      const short* __restrict__ rwb, short* __restrict__ Q,
                      int n, int layer){
  int wid = threadIdx.x>>6, lane = threadIdx.x&63;
  int node = blockIdx.x*4 + wid;
  if(node>=n) return;
  int s = rs[node], e = rs[node+1];
  float accq[16];
#pragma unroll
  for(int k=0;k<16;k++) accq[k]=0.f;
  if(e > s){
    float mx = -INFINITY;
    for(int i=s+lane;i<e;i+=64){
      int rid = rel_ids[i]; float rv = rel_vals[i];
      float a = 0.f;
      if(rv>0.f){
        float t = tp[adj_col[i]];
        float sc = rv*rsqrtf(fmaxf(rv*rv*ss_rel[rid],1e-12f));
        a = t*sc*(flag[i]? att_t[rid] : att_n[rid]);
      }
      mx = fmaxf(mx,a);
    }
    mx = waveMax(mx);
    float se = 0.f;
    for(int i=s+lane;i<e;i+=64){
      int rid = rel_ids[i]; float rv = rel_vals[i];
      float a = 0.f;
      if(rv>0.f){
        float t = tp[adj_col[i]];
        float sc = rv*rsqrtf(fmaxf(rv*rv*ss_rel[rid],1e-12f));
        a = t*sc*(flag[i]? att_t[rid] : att_n[rid]);
      }
      se += __expf(a-mx);
    }
    se = waveSum(se);
    float inv = 1.f/se;
    int qid = lane>>4, ql = lane&15;
    for(int i0=s; i0<e; i0+=4){
      int j = i0 + qid;
      float w=0.f, coef=0.f;
      float nbv[16], rbv[16];
#pragma unroll
      for(int k=0;k<16;k++){ nbv[k]=0.f; rbv[k]=0.f; }
      if(j < e){
        int rid = rel_ids[j]; float rv = rel_vals[j]; int col = adj_col[j];
        const short* np = Q + (size_t)col*QSTR + layer*D + ql*16;
        bf16x8 n0 = *(const bf16x8*)np;
        bf16x8 n1 = *(const bf16x8*)(np+8);
#pragma unroll
        for(int k=0;k<8;k++){ nbv[k]=bf2f(n0[k]); nbv[k+8]=bf2f(n1[k]); }
        if(rv>0.f){
          float t = tp[col];
          float sc = rv*rsqrtf(fmaxf(rv*rv*ss_rel[rid],1e-12f));
          bool f = flag[j];
          const short* rp = (f? rwb : reb) + (size_t)rid*D + ql*16;
          bf16x8 r0 = *(const bf16x8*)rp;
          bf16x8 r1 = *(const bf16x8*)(rp+8);
#pragma unroll
          for(int k=0;k<8;k++){ rbv[k]=bf2f(r0[k]); rbv[k+8]=bf2f(r1[k]); }
          float dp = 0.f;
#pragma unroll
          for(int k=0;k<16;k++) dp += nbv[k]*rbv[k];
#pragma unroll
          for(int o=1;o<16;o<<=1) dp += __shfl_xor(dp,o,64);
          float a = t*sc*(f? att_t[rid] : att_n[rid]);
          w = __expf(a-mx)*inv;
          coef = 2.f*t*t*sc*sc*dp;
        } else {
          w = __expf(-mx)*inv;
        }
      }
#pragma unroll
      for(int k=0;k<16;k++) accq[k] += w*(nbv[k] - coef*rbv[k]);
    }
  }
  // combine quarters
#pragma unroll
  for(int k=0;k<16;k++){
    float v = accq[k];
    v += __shfl_xor(v,16,64);
    v += __shfl_xor(v,32,64);
    accq[k] = v;
  }
  if((lane>>4)==0){
    float t0 = tp[node];
    bf16x8 o0, o1;
#pragma unroll
    for(int k=0;k<8;k++){ o0[k]=cvt_bf16(accq[k]*t0); o1[k]=cvt_bf16(accq[k+8]*t0); }
    short* op = Q + (size_t)node*QSTR + (layer+1)*D + (lane&15)*16;
    *(bf16x8*)op = o0;
    *(bf16x8*)(op+8) = o1;
  }
}

// l2-normalize proxy rows -> bf16 [128][768]
__global__ void k_proxynorm(const float* __restrict__ proxy, short* __restrict__ pn){
  __shared__ float sm[4];
  int j = blockIdx.x;
  float ssum=0.f;
  for(int d=threadIdx.x; d<DCAT; d+=256){ float v=proxy[(size_t)j*DCAT+d]; ssum+=v*v; }
  int lane=threadIdx.x&63, wid=threadIdx.x>>6;
  ssum = waveSum(ssum);
  if(lane==0) sm[wid]=ssum;
  __syncthreads();
  float scale = rsqrtf(fmaxf(sm[0]+sm[1]+sm[2]+sm[3],1e-12f));
  for(int d=threadIdx.x; d<DCAT; d+=256)
    pn[(size_t)j*DCAT + d] = cvt_bf16(proxy[(size_t)j*DCAT+d]*scale);
}

__global__ void k_cast(const float* __restrict__ in, short* __restrict__ out, long total){
  long i = (long)blockIdx.x*blockDim.x+threadIdx.x;
  if(i<total) out[i]=cvt_bf16(in[i]);
}

// transpose-cast: fp32 in[R][C] -> bf16 out[cc*ldo + coff + rr] (* sign)
__global__ void k_tcast(const float* __restrict__ in, short* __restrict__ out,
                        int R, int C, int ldo, int coff, float sign){
  __shared__ float tile[32][33];
  int bx = blockIdx.x*32, by = blockIdx.y*32;
  for(int i=threadIdx.y;i<32;i+=8){
    int rr = by+i, cc = bx+threadIdx.x;
    if(rr<R && cc<C) tile[i][threadIdx.x] = in[(size_t)rr*C + cc];
  }
  __syncthreads();
  for(int i=threadIdx.y;i<32;i+=8){
    int cc = bx+i, rr = by+threadIdx.x;
    if(cc<C && rr<R) out[(size_t)cc*ldo + coff + rr] = cvt_bf16(sign*tile[threadIdx.x][i]);
  }
}

// per-row inverse l2 norm of Q cols 0..767
__global__ void k_sn(const short* __restrict__ Q, float* __restrict__ sn, int n){
  int wid=threadIdx.x>>6, lane=threadIdx.x&63;
  int row = blockIdx.x*4+wid; if(row>=n) return;
  const short* o = Q + (size_t)row*QSTR;
  float ss=0.f;
#pragma unroll
  for(int c=0;c<3;c++){
    short4 v = *(const short4*)(o + c*256 + lane*4);
    float a=bf2f(v.x),b=bf2f(v.y),cc=bf2f(v.z),d=bf2f(v.w);
    ss += a*a+b*b+cc*cc+d*d;
  }
  ss = waveSum(ss);
  if(lane==0) sn[row]=rsqrtf(fmaxf(ss,1e-12f));
}

// row softmax over 128 logits -> bf16 probs into Q cols 768..895
__global__ void k_sm128(const float* __restrict__ P, short* __restrict__ Q, int n){
  int wid=threadIdx.x>>6, lane=threadIdx.x&63;
  int row=blockIdx.x*4+wid; if(row>=n) return;
  const float* pr = P + (size_t)row*NPX;
  float a=pr[lane], b=pr[lane+64];
  float m = waveMax(fmaxf(a,b));
  float ea=__expf(a-m), eb=__expf(b-m);
  float s = waveSum(ea+eb);
  short* pb = Q + (size_t)row*QSTR + DCAT;
  pb[lane]=cvt_bf16(ea/s); pb[lane+64]=cvt_bf16(eb/s);
}

// ---------------- MFMA GEMM, ring-3 counted-vmcnt pipeline + chunk-XOR swizzle -----
// LDS row = 32 shorts (64 B) = 4 chunks of 16 B. Involution: chunk c of row r holds
// global chunk c ^ ((r>>1)&3). Stage pre-swizzles the GLOBAL source (same 64-B span,
// coalescing preserved); fragment reads XOR kg with ((lr>>1)&3). 16-lane fragment
// reads then hit bank-starts {0,4,..,28} exactly twice = 2-way free minimum.
// V=0: outF = acc*sn[row]   V=1: outB = bf16(sigmoid(acc))   V=3: outF = acc
template<int LDA_, int LDB_, int NTOT, int KC, int V>
__global__ __launch_bounds__(256,2) void k_gemm(
    const short* __restrict__ A, const short* __restrict__ Bt,
    const float* __restrict__ sn,
    float* __restrict__ outF, short* __restrict__ outB, int M)
{
  __shared__ short smem[3][2][128*32];
  const int tid = threadIdx.x;
  const int lane = tid & 63, w = tid >> 6;
  const int wm = w >> 1, wn = w & 1;
  const int gx = gridDim.x;
  int nwg = gx*gridDim.y;
  int orig = blockIdx.y*gx + blockIdx.x;
  int q = nwg>>3, rm = nwg&7, xcd = orig&7, lid = orig>>3;
  int wg = (xcd<rm ? xcd*(q+1) : rm*(q+1)+(xcd-rm)*q) + lid;
  const int bn = (wg%gx)*128, bm = (wg/gx)*128;

  const short* Ag = A  + (size_t)bm * LDA_;
  const short* Bg = Bt + (size_t)bn * LDB_;

  auto stage = [&](int buf, int k0){
#pragma unroll
    for(int c=0;c<2;++c){
      int u = c*256 + tid;
      int row = u >> 2;
      int cb = ((u & 3) ^ ((u >> 3) & 3)) * 8;   // source chunk swizzle (involution)
      __builtin_amdgcn_global_load_lds(
        (const __attribute__((address_space(1))) unsigned int*)(Ag + (size_t)row*LDA_ + k0 + cb),
        (__attribute__((address_space(3))) unsigned int*)&smem[buf][0][u*8], 16, 0, 0);
      __builtin_amdgcn_global_load_lds(
        (const __attribute__((address_space(1))) unsigned int*)(Bg + (size_t)row*LDB_ + k0 + cb),
        (__attribute__((address_space(3))) unsigned int*)&smem[buf][1][u*8], 16, 0, 0);
    }
  };

  f32x4 acc[4][4] = {};
  const int lr = lane & 15, kg = lane >> 4;
  const int ksw = (kg ^ ((lr >> 1) & 3)) * 8;   // swizzled k-chunk (shorts)
  constexpr int NT = KC / 32;

  stage(0, 0);
  stage(1, 32);
  for(int t=0; t<NT; ++t){
    if(t+1 < NT) asm volatile("s_waitcnt vmcnt(4)" ::: "memory");
    else         asm volatile("s_waitcnt vmcnt(0)" ::: "memory");
    __builtin_amdgcn_s_barrier();
    __builtin_amdgcn_sched_barrier(0);
    const short* Al = &smem[t%3][0][0];
    const short* Bl = &smem[t%3][1][0];
    bf16x8 af[4], bfr[4];
#pragma unroll
    for(int i=0;i<4;++i)
      af[i] = *(const bf16x8*)(Al + (wm*64 + i*16 + lr)*32 + ksw);
#pragma unroll
    for(int j=0;j<4;++j)
      bfr[j] = *(const bf16x8*)(Bl + (wn*64 + j*16 + lr)*32 + ksw);
    if(t+2 < NT) stage((t+2)%3, (t+2)*32);
    __builtin_amdgcn_s_setprio(1);
#pragma unroll
    for(int i=0;i<4;++i)
#pragma unroll
      for(int j=0;j<4;++j)
        acc[i][j] = __builtin_amdgcn_mfma_f32_16x16x32_bf16(af[i], bfr[j], acc[i][j], 0, 0, 0);
    __builtin_amdgcn_s_setprio(0);
  }

  const int row0 = bm + wm*64 + (lane>>4)*4;
  const int col0 = bn + wn*64 + lr;
#pragma unroll
  for(int i=0;i<4;++i){
#pragma unroll
    for(int j=0;j<4;++j){
      int col = col0 + j*16;
#pragma unroll
      for(int r=0;r<4;++r){
        int row = row0 + i*16 + r;
        if(row < M){
          float v = acc[i][j][r];
          if constexpr (V == 0){
            outF[(size_t)row*NTOT + col] = v * sn[row];
          } else if constexpr (V == 1){
            outB[(size_t)row*NTOT + col] = cvt_bf16(1.f/(1.f+__expf(-v)));
          } else {
            outF[(size_t)row*NTOT + col] = v;
          }
        }
      }
    }
  }
}

// ---------------- k_out: out = oc - (1-g)*(P@proxy), K=128, no staging ------------
#define CSTR 136   // padded LDS row stride (shorts): 272 B, 16B-aligned, 4-bank shift/row
__global__ __launch_bounds__(256) void k_out(
    const short* __restrict__ Q, const short* __restrict__ Bt2,
    const short* __restrict__ gbuf, float* __restrict__ outF, int M)
{
  __shared__ short cst[128*CSTR];
  const int tid = threadIdx.x, lane = tid&63, w = tid>>6;
  const int wm = w>>1, wn = w&1;
  const int gx = gridDim.x;
  int nwg = gx*gridDim.y;
  int orig = blockIdx.y*gx + blockIdx.x;
  int q8 = nwg>>3, rm = nwg&7, xcd = orig&7, lid = orig>>3;
  int wg = (xcd<rm ? xcd*(q8+1) : rm*(q8+1)+(xcd-rm)*q8) + lid;
  const int bn = (wg%gx)*128, bm = (wg/gx)*128;
  const int lr = lane&15, kg = lane>>4;

  f32x4 acc[4][4] = {};
#pragma unroll
  for(int ks=0; ks<4; ++ks){
    bf16x8 af[4], bb[4];
#pragma unroll
    for(int i=0;i<4;++i)
      af[i] = *(const bf16x8*)(Q + (size_t)(bm + wm*64 + i*16 + lr)*QSTR + DCAT + ks*32 + kg*8);
#pragma unroll
    for(int j=0;j<4;++j)
      bb[j] = *(const bf16x8*)(Bt2 + (size_t)(bn + wn*64 + j*16 + lr)*NPX + ks*32 + kg*8);
#pragma unroll
    for(int i=0;i<4;++i)
#pragma unroll
      for(int j=0;j<4;++j)
        acc[i][j] = __builtin_amdgcn_mfma_f32_16x16x32_bf16(af[i], bb[j], acc[i][j], 0, 0, 0);
  }
#pragma unroll
  for(int i=0;i<4;++i)
#pragma unroll
    for(int j=0;j<4;++j)
#pragma unroll
      for(int r2=0;r2<4;++r2)
        cst[(wm*64 + i*16 + kg*4 + r2)*CSTR + wn*64 + j*16 + lr] = cvt_bf16(acc[i][j][r2]);
  __syncthreads();
  const int rl0 = tid>>4, c0 = (tid&15)*8;
#pragma unroll
  for(int rr=0; rr<8; ++rr){
    int rl = rl0 + rr*16;
    int rg = bm + rl;
    if(rg >= M) continue;
    bf16x8 c8  = *(const bf16x8*)(cst + rl*CSTR + c0);
    bf16x8 oc8 = *(const bf16x8*)(Q + (size_t)rg*QSTR + bn + c0);
    bf16x8 g8  = *(const bf16x8*)(gbuf + (size_t)rg*DCAT + bn + c0);
    float ov[8];
#pragma unroll
    for(int k=0;k<8;k++){
      float g = bf2f(g8[k]);
      ov[k] = bf2f(oc8[k]) - (1.f-g)*bf2f(c8[k]);
    }
    *(float4*)(outF + (size_t)rg*DCAT + bn + c0)     = make_float4(ov[0],ov[1],ov[2],ov[3]);
    *(float4*)(outF + (size_t)rg*DCAT + bn + c0 + 4) = make_float4(ov[4],ov[5],ov[6],ov[7]);
  }
}

__global__ void k_copyp(const float* __restrict__ p, float* __restrict__ out, int n){
  int i = blockIdx.x*blockDim.x+threadIdx.x;
  if(i<n) out[i]=p[i];
}

extern "C" void kernel_launch(void* const* d_in, const int* in_sizes, int n_in,
                              void* d_out, int out_size, void* d_ws, size_t ws_size,
                              hipStream_t stream){
  const float* features = (const float*)d_in[0];
  const float* rel_emb  = (const float*)d_in[1];
  const float* p        = (const float*)d_in[2];
  const float* w_keys   = (const float*)d_in[3];
  const float* attn     = (const float*)d_in[4];
  const float* proxy    = (const float*)d_in[5];
  const float* gatek    = (const float*)d_in[6];
  const float* rel_vals = (const float*)d_in[7];
  const int* adj_row    = (const int*)d_in[8];
  const int* adj_col    = (const int*)d_in[9];
  const int* rel_ids    = (const int*)d_in[10];
  const int* new_idx    = (const int*)d_in[11];

  const int n    = in_sizes[2];
  const int r    = in_sizes[1]/D;
  const int e    = in_sizes[7];
  const int ksel = in_sizes[11];
  const size_t Mpad = ((size_t)n + 127) & ~(size_t)127;

  char* ws = (char*)d_ws;
  size_t off=0;
  auto alloc=[&](size_t bytes)->void*{ void* pp = ws+off; off=(off+bytes+255)&~(size_t)255; return pp; };
  float* tp      = (float*)alloc((size_t)n*4);
  int*   rs      = (int*)alloc((size_t)(n+1)*4);
  unsigned char* flag = (unsigned char*)alloc((size_t)e);
  float* ss_rel  = (float*)alloc((size_t)r*4);
  float* att_n   = (float*)alloc((size_t)2*r*4);
  float* att_t   = (float*)alloc((size_t)2*r*4);
  short* reb     = (short*)alloc((size_t)r*D*2);         // rel_emb bf16
  short* rwb     = (short*)alloc((size_t)2*r*D*2);       // relW bf16 (2 layers)
  short* pn      = (short*)alloc((size_t)NPX*DCAT*2);    // l2n(proxy) bf16 [128,768]
  short* proxyb  = (short*)alloc((size_t)NPX*DCAT*2);    // proxy bf16
  short* Bt2     = (short*)alloc((size_t)DCAT*NPX*2);    // proxy^T bf16 [768,128]
  short* BG      = (short*)alloc((size_t)DCAT*QSTR*2);   // [gk^T | -(proxy@gk)^T] [768,896]
  float* MxF     = (float*)alloc((size_t)NPX*DCAT*4);    // proxy@gk fp32
  float* sn      = (float*)alloc(Mpad*4);
  float* P       = (float*)alloc(Mpad*NPX*4);            // proxy-att logits fp32
  short* gbuf    = (short*)alloc(Mpad*DCAT*2);           // gate bf16
  short* Q       = (short*)alloc(Mpad*QSTR*2);           // [outcat | probs] bf16

  float* outF = (float*)d_out;
  float* pout = (float*)d_out + (size_t)n*DCAT;

  hipMemsetAsync(flag, 0, (size_t)e, stream);
  hipMemsetAsync(Q + (size_t)n*QSTR, 0, (Mpad-(size_t)n)*QSTR*2, stream);

  k_tanh<<<(n+255)/256,256,0,stream>>>(p,tp,n);
  k_rowstart<<<(n+256)/256,256,0,stream>>>(adj_row,rs,n,e);
  k_flag<<<(ksel+255)/256,256,0,stream>>>(new_idx,flag,ksel);
  k_relprep<<<r,256,0,stream>>>(rel_emb,attn,ss_rel,att_n,r);
  {
    long tre = (long)r*D;
    k_cast<<<(int)((tre+255)/256),256,0,stream>>>(rel_emb, reb, tre);
  }
  for(int l=0;l<2;l++)
    k_relW<<<r,256,0,stream>>>(rel_emb, w_keys+(size_t)l*D*D, attn+(size_t)l*D,
                               rwb+(size_t)l*r*D, att_t+(size_t)l*r, r);
  k_proxynorm<<<NPX,256,0,stream>>>(proxy,pn);
  {
    long tpx = (long)NPX*DCAT;
    k_cast<<<(int)((tpx+255)/256),256,0,stream>>>(proxy, proxyb, tpx);
    dim3 tb(32,8);
    k_tcast<<<dim3(DCAT/32, DCAT/32), tb, 0, stream>>>(gatek, BG, DCAT, DCAT, QSTR, 0, 1.f);
    k_gemm<DCAT, QSTR, DCAT, DCAT, 3><<<dim3(DCAT/128,1),256,0,stream>>>(
        proxyb, BG, nullptr, MxF, nullptr, NPX);
    k_tcast<<<dim3(DCAT/32, NPX/32), tb, 0, stream>>>(MxF, BG, NPX, DCAT, QSTR, DCAT, -1.f);
    k_tcast<<<dim3(DCAT/32, NPX/32), tb, 0, stream>>>(proxy, Bt2, NPX, DCAT, NPX, 0, 1.f);
  }
  long tot0 = (long)n*D;
  k_init0<<<(int)((tot0+255)/256),256,0,stream>>>(features,tp,Q,tot0);
  for(int l=0;l<2;l++)
    k_agg<<<(n+3)/4,256,0,stream>>>(rs,adj_col,rel_ids,rel_vals,flag,tp,ss_rel,
                                    att_n+(size_t)l*r, att_t+(size_t)l*r, reb,
                                    rwb+(size_t)l*r*D, Q, n, l);
  k_sn<<<(n+3)/4,256,0,stream>>>(Q,sn,n);

  int mt = (int)(Mpad/128);
  // GEMM-1: P = (Q[:, :768] @ pn^T) * sn[row]   [M,128], K=768
  k_gemm<QSTR, DCAT, NPX, DCAT, 0><<<dim3(1, mt),256,0,stream>>>(
      Q, pn, sn, P, nullptr, n);
  k_sm128<<<(n+3)/4,256,0,stream>>>(P,Q,n);
  // kG: gate = sigmoid(Q[:, :896] @ BG^T)   [M,768], K=896
  k_gemm<QSTR, QSTR, DCAT, QSTR, 1><<<dim3(DCAT/128, mt),256,0,stream>>>(
      Q, BG, nullptr, nullptr, gbuf, n);
  // k_out: out = oc - (1-g)*(P@proxy)   [M,768], K=128
  k_out<<<dim3(DCAT/128, mt),256,0,stream>>>(Q, Bt2, gbuf, outF, n);
  k_copyp<<<(n+255)/256,256,0,stream>>>(p,pout,n);
}

// Round 7
// 512.481 us; speedup vs baseline: 1.2844x; 1.0881x over previous
//
#include <hip/hip_runtime.h>
#include <math.h>

#define D 256
#define DCAT 768
#define NPX 128
#define QSTR 896   // Q row stride: [outcat(768) | P(128)] bf16
#define CSTR 136   // padded LDS row stride (shorts) for epilogue transpose

typedef __attribute__((ext_vector_type(8))) short bf16x8;
typedef __attribute__((ext_vector_type(4))) float f32x4;

__device__ __forceinline__ short cvt_bf16(float f){
  union { float f; unsigned u; } v; v.f = f;
  unsigned r = v.u + 0x7FFF + ((v.u >> 16) & 1);   // RNE
  return (short)(r >> 16);
}
__device__ __forceinline__ float bf2f(short s){
  union { float f; unsigned u; } v; v.u = ((unsigned)(unsigned short)s) << 16;
  return v.f;
}

__device__ __forceinline__ float waveSum(float v){
#pragma unroll
  for(int o=32;o>=1;o>>=1) v += __shfl_xor(v,o,64);
  return v;
}
__device__ __forceinline__ float waveMax(float v){
#pragma unroll
  for(int o=32;o>=1;o>>=1) v = fmaxf(v,__shfl_xor(v,o,64));
  return v;
}

// merged: tanh(p), rowstart binary search, new_indices flag
__global__ void k_prep(const float* __restrict__ p, float* __restrict__ tp,
                       const int* __restrict__ adj_row, int* __restrict__ rs,
                       const int* __restrict__ idx, unsigned char* __restrict__ flag,
                       int n, int e, int ksel){
  int i = blockIdx.x*blockDim.x+threadIdx.x;
  if(i<n) tp[i]=tanhf(p[i]);
  if(i<=n){
    int lo=0, hi=e;
    while(lo<hi){ int mid=(lo+hi)>>1; if(adj_row[mid]<i) lo=mid+1; else hi=mid; }
    rs[i]=lo;
  }
  if(i<ksel) flag[idx[i]] = 1;
}

// per-relation: sum of squares + dot(rel_emb_row, attn_kernel_l) + bf16 cast
__global__ void k_relprep(const float* __restrict__ rel_emb, const float* __restrict__ attn,
                          float* __restrict__ ss_rel, float* __restrict__ att_n,
                          short* __restrict__ reb, int R_){
  __shared__ float sm[4];
  int r = blockIdx.x; int d = threadIdx.x;
  float v = rel_emb[(size_t)r*D+d];
  reb[(size_t)r*D+d] = cvt_bf16(v);
  int lane=threadIdx.x&63, wid=threadIdx.x>>6;
  float s = waveSum(v*v);
  if(lane==0) sm[wid]=s;
  __syncthreads();
  if(threadIdx.x==0) ss_rel[r]=sm[0]+sm[1]+sm[2]+sm[3];
  __syncthreads();
  for(int l=0;l<2;l++){
    float dd = waveSum(v*attn[l*D+d]);
    if(lane==0) sm[wid]=dd;
    __syncthreads();
    if(threadIdx.x==0) att_n[(size_t)l*R_+r]=sm[0]+sm[1]+sm[2]+sm[3];
    __syncthreads();
  }
}

// per-relation: rel_emb_row @ W -> bf16 table (and fp32 dot with attn kernel)
__global__ void k_relW(const float* __restrict__ rel_emb, const float* __restrict__ W,
                       const float* __restrict__ ak, short* __restrict__ rwb,
                       float* __restrict__ att_t, int R_){
  __shared__ float sm[4];
  int r=blockIdx.x, d=threadIdx.x;
  const float* row = rel_emb + (size_t)r*D;
  float acc=0.f;
#pragma unroll 4
  for(int k=0;k<D;k++) acc = fmaf(row[k], W[(size_t)k*D+d], acc);
  rwb[(size_t)r*D+d]=cvt_bf16(acc);
  int lane=threadIdx.x&63, wid=threadIdx.x>>6;
  float dd = waveSum(acc*ak[d]);
  if(lane==0) sm[wid]=dd;
  __syncthreads();
  if(threadIdx.x==0) att_t[r]=sm[0]+sm[1]+sm[2]+sm[3];
}

__global__ void k_init0(const float* __restrict__ features, const float* __restrict__ tp,
                        short* __restrict__ Q, long total){
  long i = (long)blockIdx.x*blockDim.x+threadIdx.x;
  if(i >= total) return;
  int row = (int)(i>>8), d = (int)(i&255);
  Q[(size_t)row*QSTR + d] = cvt_bf16(features[i]*tp[row]);
}

// one wave per node; main loop quarter-wave-parallel (4 edges in flight)
__global__ void k_agg(const int* __restrict__ rs, const int* __restrict__ adj_col,
                      const int* __restrict__ rel_ids, const float* __restrict__ rel_vals,
                      const unsigned char* __restrict__ flag, const float* __restrict__ tp,
                      const float* __restrict__ ss_rel, const float* __restrict__ att_n,
                      const float* __restrict__ att_t, const short* __restrict__ reb,
                      const short* __restrict__ rwb, short* __restrict__ Q,
                      int n, int layer){
  int wid = threadIdx.x>>6, lane = threadIdx.x&63;
  int node = blockIdx.x*4 + wid;
  if(node>=n) return;
  int s = rs[node], e = rs[node+1];
  float accq[16];
#pragma unroll
  for(int k=0;k<16;k++) accq[k]=0.f;
  if(e > s){
    float mx = -INFINITY;
    for(int i=s+lane;i<e;i+=64){
      int rid = rel_ids[i]; float rv = rel_vals[i];
      float a = 0.f;
      if(rv>0.f){
        float t = tp[adj_col[i]];
        float sc = rv*rsqrtf(fmaxf(rv*rv*ss_rel[rid],1e-12f));
        a = t*sc*(flag[i]? att_t[rid] : att_n[rid]);
      }
      mx = fmaxf(mx,a);
    }
    mx = waveMax(mx);
    float se = 0.f;
    for(int i=s+lane;i<e;i+=64){
      int rid = rel_ids[i]; float rv = rel_vals[i];
      float a = 0.f;
      if(rv>0.f){
        float t = tp[adj_col[i]];
        float sc = rv*rsqrtf(fmaxf(rv*rv*ss_rel[rid],1e-12f));
        a = t*sc*(flag[i]? att_t[rid] : att_n[rid]);
      }
      se += __expf(a-mx);
    }
    se = waveSum(se);
    float inv = 1.f/se;
    int qid = lane>>4, ql = lane&15;
    for(int i0=s; i0<e; i0+=4){
      int j = i0 + qid;
      float w=0.f, coef=0.f;
      float nbv[16], rbv[16];
#pragma unroll
      for(int k=0;k<16;k++){ nbv[k]=0.f; rbv[k]=0.f; }
      if(j < e){
        int rid = rel_ids[j]; float rv = rel_vals[j]; int col = adj_col[j];
        const short* np = Q + (size_t)col*QSTR + layer*D + ql*16;
        bf16x8 n0 = *(const bf16x8*)np;
        bf16x8 n1 = *(const bf16x8*)(np+8);
#pragma unroll
        for(int k=0;k<8;k++){ nbv[k]=bf2f(n0[k]); nbv[k+8]=bf2f(n1[k]); }
        if(rv>0.f){
          float t = tp[col];
          float sc = rv*rsqrtf(fmaxf(rv*rv*ss_rel[rid],1e-12f));
          bool f = flag[j];
          const short* rp = (f? rwb : reb) + (size_t)rid*D + ql*16;
          bf16x8 r0 = *(const bf16x8*)rp;
          bf16x8 r1 = *(const bf16x8*)(rp+8);
#pragma unroll
          for(int k=0;k<8;k++){ rbv[k]=bf2f(r0[k]); rbv[k+8]=bf2f(r1[k]); }
          float dp = 0.f;
#pragma unroll
          for(int k=0;k<16;k++) dp += nbv[k]*rbv[k];
#pragma unroll
          for(int o=1;o<16;o<<=1) dp += __shfl_xor(dp,o,64);
          float a = t*sc*(f? att_t[rid] : att_n[rid]);
          w = __expf(a-mx)*inv;
          coef = 2.f*t*t*sc*sc*dp;
        } else {
          w = __expf(-mx)*inv;
        }
      }
#pragma unroll
      for(int k=0;k<16;k++) accq[k] += w*(nbv[k] - coef*rbv[k]);
    }
  }
#pragma unroll
  for(int k=0;k<16;k++){
    float v = accq[k];
    v += __shfl_xor(v,16,64);
    v += __shfl_xor(v,32,64);
    accq[k] = v;
  }
  if((lane>>4)==0){
    float t0 = tp[node];
    bf16x8 o0, o1;
#pragma unroll
    for(int k=0;k<8;k++){ o0[k]=cvt_bf16(accq[k]*t0); o1[k]=cvt_bf16(accq[k+8]*t0); }
    short* op = Q + (size_t)node*QSTR + (layer+1)*D + (lane&15)*16;
    *(bf16x8*)op = o0;
    *(bf16x8*)(op+8) = o1;
  }
}

// l2-normalize proxy rows -> bf16 [128][768]
__global__ void k_proxynorm(const float* __restrict__ proxy, short* __restrict__ pn){
  __shared__ float sm[4];
  int j = blockIdx.x;
  float ssum=0.f;
  for(int d=threadIdx.x; d<DCAT; d+=256){ float v=proxy[(size_t)j*DCAT+d]; ssum+=v*v; }
  int lane=threadIdx.x&63, wid=threadIdx.x>>6;
  ssum = waveSum(ssum);
  if(lane==0) sm[wid]=ssum;
  __syncthreads();
  float scale = rsqrtf(fmaxf(sm[0]+sm[1]+sm[2]+sm[3],1e-12f));
  for(int d=threadIdx.x; d<DCAT; d+=256)
    pn[(size_t)j*DCAT + d] = cvt_bf16(proxy[(size_t)j*DCAT+d]*scale);
}

__global__ void k_cast(const float* __restrict__ in, short* __restrict__ out, long total){
  long i = (long)blockIdx.x*blockDim.x+threadIdx.x;
  if(i<total) out[i]=cvt_bf16(in[i]);
}

// transpose-cast: fp32 in[R][C] -> bf16 out[cc*ldo + coff + rr] (* sign)
__global__ void k_tcast(const float* __restrict__ in, short* __restrict__ out,
                        int R, int C, int ldo, int coff, float sign){
  __shared__ float tile[32][33];
  int bx = blockIdx.x*32, by = blockIdx.y*32;
  for(int i=threadIdx.y;i<32;i+=8){
    int rr = by+i, cc = bx+threadIdx.x;
    if(rr<R && cc<C) tile[i][threadIdx.x] = in[(size_t)rr*C + cc];
  }
  __syncthreads();
  for(int i=threadIdx.y;i<32;i+=8){
    int cc = bx+i, rr = by+threadIdx.x;
    if(cc<C && rr<R) out[(size_t)cc*ldo + coff + rr] = cvt_bf16(sign*tile[threadIdx.x][i]);
  }
}

// per-row inverse l2 norm of Q cols 0..767
__global__ void k_sn(const short* __restrict__ Q, float* __restrict__ sn, int n){
  int wid=threadIdx.x>>6, lane=threadIdx.x&63;
  int row = blockIdx.x*4+wid; if(row>=n) return;
  const short* o = Q + (size_t)row*QSTR;
  float ss=0.f;
#pragma unroll
  for(int c=0;c<3;c++){
    short4 v = *(const short4*)(o + c*256 + lane*4);
    float a=bf2f(v.x),b=bf2f(v.y),cc=bf2f(v.z),d=bf2f(v.w);
    ss += a*a+b*b+cc*cc+d*d;
  }
  ss = waveSum(ss);
  if(lane==0) sn[row]=rsqrtf(fmaxf(ss,1e-12f));
}

// ---------------- generic MFMA GEMM (ring-3, plain fp32 out) — used for Mx only ----
template<int LDA_, int LDB_, int NTOT, int KC>
__global__ __launch_bounds__(256,2) void k_gemm(
    const short* __restrict__ A, const short* __restrict__ Bt,
    float* __restrict__ outF, int M)
{
  __shared__ short smem[3][2][128*32];
  const int tid = threadIdx.x;
  const int lane = tid & 63, w = tid >> 6;
  const int wm = w >> 1, wn = w & 1;
  const int bn = blockIdx.x * 128, bm = blockIdx.y * 128;

  const short* Ag = A  + (size_t)bm * LDA_;
  const short* Bg = Bt + (size_t)bn * LDB_;

  auto stage = [&](int buf, int k0){
#pragma unroll
    for(int c=0;c<2;++c){
      int u = c*256 + tid;
      int row = u >> 2;
      int cb = ((u & 3) ^ ((u >> 3) & 3)) * 8;
      __builtin_amdgcn_global_load_lds(
        (const __attribute__((address_space(1))) unsigned int*)(Ag + (size_t)row*LDA_ + k0 + cb),
        (__attribute__((address_space(3))) unsigned int*)&smem[buf][0][u*8], 16, 0, 0);
      __builtin_amdgcn_global_load_lds(
        (const __attribute__((address_space(1))) unsigned int*)(Bg + (size_t)row*LDB_ + k0 + cb),
        (__attribute__((address_space(3))) unsigned int*)&smem[buf][1][u*8], 16, 0, 0);
    }
  };

  f32x4 acc[4][4] = {};
  const int lr = lane & 15, kg = lane >> 4;
  const int ksw = (kg ^ ((lr >> 1) & 3)) * 8;
  constexpr int NT = KC / 32;

  stage(0, 0);
  stage(1, 32);
  for(int t=0; t<NT; ++t){
    if(t+1 < NT) asm volatile("s_waitcnt vmcnt(4)" ::: "memory");
    else         asm volatile("s_waitcnt vmcnt(0)" ::: "memory");
    __builtin_amdgcn_s_barrier();
    __builtin_amdgcn_sched_barrier(0);
    const short* Al = &smem[t%3][0][0];
    const short* Bl = &smem[t%3][1][0];
    bf16x8 af[4], bfr[4];
#pragma unroll
    for(int i=0;i<4;++i) af[i] = *(const bf16x8*)(Al + (wm*64 + i*16 + lr)*32 + ksw);
#pragma unroll
    for(int j=0;j<4;++j) bfr[j] = *(const bf16x8*)(Bl + (wn*64 + j*16 + lr)*32 + ksw);
    if(t+2 < NT) stage((t+2)%3, (t+2)*32);
    __builtin_amdgcn_s_setprio(1);
#pragma unroll
    for(int i=0;i<4;++i)
#pragma unroll
      for(int j=0;j<4;++j)
        acc[i][j] = __builtin_amdgcn_mfma_f32_16x16x32_bf16(af[i], bfr[j], acc[i][j], 0, 0, 0);
    __builtin_amdgcn_s_setprio(0);
  }

  const int row0 = bm + wm*64 + (lane>>4)*4;
  const int col0 = bn + wn*64 + lr;
#pragma unroll
  for(int i=0;i<4;++i)
#pragma unroll
    for(int j=0;j<4;++j)
#pragma unroll
      for(int r=0;r<4;++r){
        int row = row0 + i*16 + r;
        if(row < M) outF[(size_t)row*NTOT + col0 + j*16] = acc[i][j][r];
      }
}

// ---------------- k_pr: proxy-att logits GEMM (K=768) + fused row softmax ---------
// P[row,:] = softmax(sn[row] * (Q[row,:768] @ pn^T))  -> bf16 into Q[:,768:896]
__global__ __launch_bounds__(256,2) void k_pr(
    short* __restrict__ Q, const short* __restrict__ pn,
    const float* __restrict__ sn, int M)
{
  __shared__ short smem[3][2][128*32];
  const int tid = threadIdx.x, lane = tid & 63, w = tid >> 6;
  const int wm = w >> 1, wn = w & 1;
  // bijective XCD swizzle over row tiles
  int nwg = gridDim.y;
  int orig = blockIdx.y;
  int q = nwg>>3, rm = nwg&7, xcd = orig&7, lid = orig>>3;
  int wg = (xcd<rm ? xcd*(q+1) : rm*(q+1)+(xcd-rm)*q) + lid;
  const int bm = wg*128;

  const short* Ag = Q + (size_t)bm * QSTR;
  const short* Bg = pn;

  auto stage = [&](int buf, int k0){
#pragma unroll
    for(int c=0;c<2;++c){
      int u = c*256 + tid;
      int row = u >> 2;
      int cb = ((u & 3) ^ ((u >> 3) & 3)) * 8;
      __builtin_amdgcn_global_load_lds(
        (const __attribute__((address_space(1))) unsigned int*)(Ag + (size_t)row*QSTR + k0 + cb),
        (__attribute__((address_space(3))) unsigned int*)&smem[buf][0][u*8], 16, 0, 0);
      __builtin_amdgcn_global_load_lds(
        (const __attribute__((address_space(1))) unsigned int*)(Bg + (size_t)row*DCAT + k0 + cb),
        (__attribute__((address_space(3))) unsigned int*)&smem[buf][1][u*8], 16, 0, 0);
    }
  };

  f32x4 acc[4][4] = {};
  const int lr = lane & 15, kg = lane >> 4;
  const int ksw = (kg ^ ((lr >> 1) & 3)) * 8;
  constexpr int NT = DCAT / 32;   // 24

  stage(0, 0);
  stage(1, 32);
  for(int t=0; t<NT; ++t){
    if(t+1 < NT) asm volatile("s_waitcnt vmcnt(4)" ::: "memory");
    else         asm volatile("s_waitcnt vmcnt(0)" ::: "memory");
    __builtin_amdgcn_s_barrier();
    __builtin_amdgcn_sched_barrier(0);
    const short* Al = &smem[t%3][0][0];
    const short* Bl = &smem[t%3][1][0];
    bf16x8 af[4], bfr[4];
#pragma unroll
    for(int i=0;i<4;++i) af[i] = *(const bf16x8*)(Al + (wm*64 + i*16 + lr)*32 + ksw);
#pragma unroll
    for(int j=0;j<4;++j) bfr[j] = *(const bf16x8*)(Bl + (wn*64 + j*16 + lr)*32 + ksw);
    if(t+2 < NT) stage((t+2)%3, (t+2)*32);
    __builtin_amdgcn_s_setprio(1);
#pragma unroll
    for(int i=0;i<4;++i)
#pragma unroll
      for(int j=0;j<4;++j)
        acc[i][j] = __builtin_amdgcn_mfma_f32_16x16x32_bf16(af[i], bfr[j], acc[i][j], 0, 0, 0);
    __builtin_amdgcn_s_setprio(0);
  }

  // logits -> LDS bf16 [128][132] (reuse ring)
  __syncthreads();
  short* lg = (short*)smem;
  const int row0l = wm*64 + kg*4;
  const int col0l = wn*64 + lr;
#pragma unroll
  for(int i=0;i<4;++i){
#pragma unroll
    for(int j=0;j<4;++j){
#pragma unroll
      for(int r=0;r<4;++r){
        int rl = row0l + i*16 + r;
        float s = sn[bm + rl];     // pad rows: acc==0, so value 0 regardless
        lg[rl*132 + col0l + j*16] = cvt_bf16(acc[i][j][r] * s);
      }
    }
  }
  __syncthreads();
  // row softmax: wave w handles rows w*32..w*32+31, 2 cols/lane
  for(int k2=0;k2<32;++k2){
    int rl = w*32 + k2;
    float a = bf2f(lg[rl*132 + lane]);
    float b = bf2f(lg[rl*132 + 64 + lane]);
    float m = waveMax(fmaxf(a,b));
    float ea = __expf(a-m), eb = __expf(b-m);
    float sm_ = waveSum(ea+eb);
    float inv = 1.f/sm_;
    size_t rg = (size_t)(bm + rl);
    Q[rg*QSTR + DCAT + lane]      = cvt_bf16(ea*inv);
    Q[rg*QSTR + DCAT + 64 + lane] = cvt_bf16(eb*inv);
  }
}

// ---------------- k_go: fused gate GEMM + output ----------------------------------
// pv = P@proxy (K=128, direct global, packed bf16 in regs);
// acc = [oc|P] @ BG^T (K=896, ring-3)  == gate logits;
// out = oc - (1-sigmoid(acc))*pv   (coalesced via LDS transpose)
__global__ __launch_bounds__(256,2) void k_go(
    short* __restrict__ Q, const short* __restrict__ BG,
    const short* __restrict__ Bt2, float* __restrict__ outF, int M)
{
  __shared__ short smem[3][2][128*32];
  const int tid = threadIdx.x, lane = tid & 63, w = tid >> 6;
  const int wm = w >> 1, wn = w & 1;
  const int gx = gridDim.x;
  int nwg = gx*gridDim.y;
  int orig = blockIdx.y*gx + blockIdx.x;
  int q = nwg>>3, rm = nwg&7, xcd = orig&7, lid = orig>>3;
  int wg = (xcd<rm ? xcd*(q+1) : rm*(q+1)+(xcd-rm)*q) + lid;
  const int bn = (wg%gx)*128, bm = (wg/gx)*128;
  const int lr = lane & 15, kg = lane >> 4;

  const short* Ag = Q  + (size_t)bm * QSTR;
  const short* Bg = BG + (size_t)bn * QSTR;

  auto stage = [&](int buf, int k0){
#pragma unroll
    for(int c=0;c<2;++c){
      int u = c*256 + tid;
      int row = u >> 2;
      int cb = ((u & 3) ^ ((u >> 3) & 3)) * 8;
      __builtin_amdgcn_global_load_lds(
        (const __attribute__((address_space(1))) unsigned int*)(Ag + (size_t)row*QSTR + k0 + cb),
        (__attribute__((address_space(3))) unsigned int*)&smem[buf][0][u*8], 16, 0, 0);
      __builtin_amdgcn_global_load_lds(
        (const __attribute__((address_space(1))) unsigned int*)(Bg + (size_t)row*QSTR + k0 + cb),
        (__attribute__((address_space(3))) unsigned int*)&smem[buf][1][u*8], 16, 0, 0);
    }
  };

  // issue first two ring stages early — phase A compute hides their latency
  stage(0, 0);
  stage(1, 32);

  // ---- phase A: pv = P @ Bt2^T (K=128, direct global MFMA) ----
  f32x4 acc[4][4] = {};
#pragma unroll
  for(int ks=0; ks<4; ++ks){
    bf16x8 af[4], bb[4];
#pragma unroll
    for(int i=0;i<4;++i)
      af[i] = *(const bf16x8*)(Q + (size_t)(bm + wm*64 + i*16 + lr)*QSTR + DCAT + ks*32 + kg*8);
#pragma unroll
    for(int j=0;j<4;++j)
      bb[j] = *(const bf16x8*)(Bt2 + (size_t)(bn + wn*64 + j*16 + lr)*NPX + ks*32 + kg*8);
#pragma unroll
    for(int i=0;i<4;++i)
#pragma unroll
      for(int j=0;j<4;++j)
        acc[i][j] = __builtin_amdgcn_mfma_f32_16x16x32_bf16(af[i], bb[j], acc[i][j], 0, 0, 0);
  }
  short4 pvb[4][4];
#pragma unroll
  for(int i=0;i<4;++i)
#pragma unroll
    for(int j=0;j<4;++j){
      pvb[i][j].x = cvt_bf16(acc[i][j][0]);
      pvb[i][j].y = cvt_bf16(acc[i][j][1]);
      pvb[i][j].z = cvt_bf16(acc[i][j][2]);
      pvb[i][j].w = cvt_bf16(acc[i][j][3]);
      acc[i][j] = (f32x4){0.f,0.f,0.f,0.f};
    }

  // ---- main loop: gate logits, K=896, ring-3 counted vmcnt ----
  const int ksw = (kg ^ ((lr >> 1) & 3)) * 8;
  constexpr int NT = QSTR / 32;   // 28
  for(int t=0; t<NT; ++t){
    if(t+1 < NT) asm volatile("s_waitcnt vmcnt(4)" ::: "memory");
    else         asm volatile("s_waitcnt vmcnt(0)" ::: "memory");
    __builtin_amdgcn_s_barrier();
    __builtin_amdgcn_sched_barrier(0);
    const short* Al = &smem[t%3][0][0];
    const short* Bl = &smem[t%3][1][0];
    bf16x8 af[4], bfr[4];
#pragma unroll
    for(int i=0;i<4;++i) af[i] = *(const bf16x8*)(Al + (wm*64 + i*16 + lr)*32 + ksw);
#pragma unroll
    for(int j=0;j<4;++j) bfr[j] = *(const bf16x8*)(Bl + (wn*64 + j*16 + lr)*32 + ksw);
    if(t+2 < NT) stage((t+2)%3, (t+2)*32);
    __builtin_amdgcn_s_setprio(1);
#pragma unroll
    for(int i=0;i<4;++i)
#pragma unroll
      for(int j=0;j<4;++j)
        acc[i][j] = __builtin_amdgcn_mfma_f32_16x16x32_bf16(af[i], bfr[j], acc[i][j], 0, 0, 0);
    __builtin_amdgcn_s_setprio(0);
  }

  // ---- epilogue: out = oc - (1-g)*pv ----
  __syncthreads();
  short* cst = (short*)smem;
  const int row0l = wm*64 + kg*4;
  const int col0l = wn*64 + lr;
#pragma unroll
  for(int i=0;i<4;++i){
#pragma unroll
    for(int j=0;j<4;++j){
      float pv4[4] = { bf2f(pvb[i][j].x), bf2f(pvb[i][j].y), bf2f(pvb[i][j].z), bf2f(pvb[i][j].w) };
#pragma unroll
      for(int r2=0;r2<4;++r2){
        float g = 1.f/(1.f+__expf(-acc[i][j][r2]));
        cst[(row0l + i*16 + r2)*CSTR + col0l + j*16] = cvt_bf16((1.f-g)*pv4[r2]);
      }
    }
  }
  __syncthreads();
  const int rl0 = tid>>4, c0 = (tid&15)*8;
#pragma unroll
  for(int rr=0; rr<8; ++rr){
    int rl = rl0 + rr*16;
    int rg = bm + rl;
    if(rg >= M) continue;
    bf16x8 c8  = *(const bf16x8*)(cst + rl*CSTR + c0);
    bf16x8 oc8 = *(const bf16x8*)(Q + (size_t)rg*QSTR + bn + c0);
    float ov[8];
#pragma unroll
    for(int k=0;k<8;k++) ov[k] = bf2f(oc8[k]) - bf2f(c8[k]);
    *(float4*)(outF + (size_t)rg*DCAT + bn + c0)     = make_float4(ov[0],ov[1],ov[2],ov[3]);
    *(float4*)(outF + (size_t)rg*DCAT + bn + c0 + 4) = make_float4(ov[4],ov[5],ov[6],ov[7]);
  }
}

__global__ void k_copyp(const float* __restrict__ p, float* __restrict__ out, int n){
  int i = blockIdx.x*blockDim.x+threadIdx.x;
  if(i<n) out[i]=p[i];
}

extern "C" void kernel_launch(void* const* d_in, const int* in_sizes, int n_in,
                              void* d_out, int out_size, void* d_ws, size_t ws_size,
                              hipStream_t stream){
  const float* features = (const float*)d_in[0];
  const float* rel_emb  = (const float*)d_in[1];
  const float* p        = (const float*)d_in[2];
  const float* w_keys   = (const float*)d_in[3];
  const float* attn     = (const float*)d_in[4];
  const float* proxy    = (const float*)d_in[5];
  const float* gatek    = (const float*)d_in[6];
  const float* rel_vals = (const float*)d_in[7];
  const int* adj_row    = (const int*)d_in[8];
  const int* adj_col    = (const int*)d_in[9];
  const int* rel_ids    = (const int*)d_in[10];
  const int* new_idx    = (const int*)d_in[11];

  const int n    = in_sizes[2];
  const int r    = in_sizes[1]/D;
  const int e    = in_sizes[7];
  const int ksel = in_sizes[11];
  const size_t Mpad = ((size_t)n + 127) & ~(size_t)127;

  char* ws = (char*)d_ws;
  size_t off=0;
  auto alloc=[&](size_t bytes)->void*{ void* pp = ws+off; off=(off+bytes+255)&~(size_t)255; return pp; };
  float* tp      = (float*)alloc((size_t)n*4);
  int*   rs      = (int*)alloc((size_t)(n+1)*4);
  unsigned char* flag = (unsigned char*)alloc((size_t)e);
  float* ss_rel  = (float*)alloc((size_t)r*4);
  float* att_n   = (float*)alloc((size_t)2*r*4);
  float* att_t   = (float*)alloc((size_t)2*r*4);
  short* reb     = (short*)alloc((size_t)r*D*2);         // rel_emb bf16
  short* rwb     = (short*)alloc((size_t)2*r*D*2);       // relW bf16 (2 layers)
  short* pn      = (short*)alloc((size_t)NPX*DCAT*2);    // l2n(proxy) bf16 [128,768]
  short* proxyb  = (short*)alloc((size_t)NPX*DCAT*2);    // proxy bf16
  short* Bt2     = (short*)alloc((size_t)DCAT*NPX*2);    // proxy^T bf16 [768,128]
  short* BG      = (short*)alloc((size_t)DCAT*QSTR*2);   // [gk^T | -(proxy@gk)^T] [768,896]
  float* MxF     = (float*)alloc((size_t)NPX*DCAT*4);    // proxy@gk fp32
  float* sn      = (float*)alloc(Mpad*4);
  short* Q       = (short*)alloc(Mpad*QSTR*2);           // [outcat | probs] bf16

  float* outF = (float*)d_out;
  float* pout = (float*)d_out + (size_t)n*DCAT;

  hipMemsetAsync(flag, 0, (size_t)e, stream);
  hipMemsetAsync(Q + (size_t)n*QSTR, 0, (Mpad-(size_t)n)*QSTR*2, stream);

  int prep_n = (ksel > n+1 ? ksel : n+1);
  k_prep<<<(prep_n+255)/256,256,0,stream>>>(p,tp,adj_row,rs,new_idx,flag,n,e,ksel);
  k_relprep<<<r,256,0,stream>>>(rel_emb,attn,ss_rel,att_n,reb,r);
  for(int l=0;l<2;l++)
    k_relW<<<r,256,0,stream>>>(rel_emb, w_keys+(size_t)l*D*D, attn+(size_t)l*D,
                               rwb+(size_t)l*r*D, att_t+(size_t)l*r, r);
  k_proxynorm<<<NPX,256,0,stream>>>(proxy,pn);
  {
    long tpx = (long)NPX*DCAT;
    k_cast<<<(int)((tpx+255)/256),256,0,stream>>>(proxy, proxyb, tpx);
    dim3 tb(32,8);
    k_tcast<<<dim3(DCAT/32, DCAT/32), tb, 0, stream>>>(gatek, BG, DCAT, DCAT, QSTR, 0, 1.f);
    k_gemm<DCAT, QSTR, DCAT, DCAT><<<dim3(DCAT/128,1),256,0,stream>>>(proxyb, BG, MxF, NPX);
    k_tcast<<<dim3(DCAT/32, NPX/32), tb, 0, stream>>>(MxF, BG, NPX, DCAT, QSTR, DCAT, -1.f);
    k_tcast<<<dim3(DCAT/32, NPX/32), tb, 0, stream>>>(proxy, Bt2, NPX, DCAT, NPX, 0, 1.f);
  }
  long tot0 = (long)n*D;
  k_init0<<<(int)((tot0+255)/256),256,0,stream>>>(features,tp,Q,tot0);
  for(int l=0;l<2;l++)
    k_agg<<<(n+3)/4,256,0,stream>>>(rs,adj_col,rel_ids,rel_vals,flag,tp,ss_rel,
                                    att_n+(size_t)l*r, att_t+(size_t)l*r, reb,
                                    rwb+(size_t)l*r*D, Q, n, l);
  k_sn<<<(n+3)/4,256,0,stream>>>(Q,sn,n);

  int mt = (int)(Mpad/128);
  // k_pr: proxy-att logits + fused softmax -> probs into Q[:,768:896]
  k_pr<<<dim3(1, mt),256,0,stream>>>(Q, pn, sn, n);
  // k_go: fused gate + output
  k_go<<<dim3(DCAT/128, mt),256,0,stream>>>(Q, BG, Bt2, outF, n);
  k_copyp<<<(n+255)/256,256,0,stream>>>(p,pout,n);
}